// Round 4
// baseline (427.337 us; speedup 1.0000x reference)
//
#include <hip/hip_runtime.h>
#include <hip/hip_cooperative_groups.h>
#include <math.h>

namespace cg = cooperative_groups;

#define S_LEN 2048
#define E_DIM 512
#define NE (S_LEN * E_DIM)
#define H_NUM 8
#define WH 32
#define NOFF 65
#define PROW (H_NUM * NOFF) /* 520 */
#define PN (S_LEN * PROW)

typedef float f32x4 __attribute__((ext_vector_type(4)));
typedef short short8 __attribute__((ext_vector_type(8)));

__device__ __forceinline__ unsigned short f2bf(float f) {
    union { float f; unsigned u; } cv; cv.f = f;
    unsigned u = cv.u;
    u += 0x7fffu + ((u >> 16) & 1u);   // RNE
    return (unsigned short)(u >> 16);
}
__device__ __forceinline__ unsigned pk2(float x, float y) {
    return (unsigned)f2bf(x) | ((unsigned)f2bf(y) << 16);
}

// Raw barrier: lgkmcnt(0) only, no vmcnt drain (T3/T4 minimum form).
#define LGKM_BARRIER() do {                                   \
    __builtin_amdgcn_sched_barrier(0);                        \
    asm volatile("s_waitcnt lgkmcnt(0)" ::: "memory");        \
    __builtin_amdgcn_s_barrier();                             \
    __builtin_amdgcn_sched_barrier(0);                        \
} while (0)

// ---------------------------------------------------------------------------
// Stage A helper (proven qkv core, parameterized LDS + half-block tid).
// 64x64 tile, 4 waves (one 256-thr half), dbuf LDS, 2-ahead prefetch,
// one lgkm-only barrier per k-step (barriers are block-wide: both halves
// execute identical, uniform barrier sequences).
// ---------------------------------------------------------------------------
__device__ __forceinline__ void gemm64(
    const float* __restrict__ A, const float* __restrict__ W,
    const float* __restrict__ bias, float* __restrict__ C,
    float scale, int m0, int n0,
    unsigned short* As, unsigned short* Bs, int htid, bool active)
{
    const int lane = htid & 63;
    const int wave = (htid >> 6) & 3;
    const int quad = lane >> 4, l16 = lane & 15;
    const int wr = (wave >> 1) * 32, wc = (wave & 1) * 32;
    const int ar = htid >> 2, ac = (htid & 3) * 8;
    const int bn = htid & 63, bk0 = ((htid >> 6) & 3) * 8;

    f32x4 acc00 = {0.f,0.f,0.f,0.f}, acc01 = acc00, acc10 = acc00, acc11 = acc00;

    const float* Arow = A + (size_t)(m0 + ar) * E_DIM;

    float4 a0r[2], a1r[2];
    float  br[2][8];

#define QLOAD(s_, i_) do {                                                    \
        int kk_ = (i_) * 32;                                                  \
        a0r[s_] = *(const float4*)(Arow + kk_ + ac);                          \
        a1r[s_] = *(const float4*)(Arow + kk_ + ac + 4);                      \
        _Pragma("unroll")                                                     \
        for (int j_ = 0; j_ < 8; ++j_)                                        \
            br[s_][j_] = W[(size_t)(kk_ + bk0 + j_) * E_DIM + n0 + bn];       \
    } while (0)

#define QPACK(s_, b_) do {                                                    \
        uint4 ap_;                                                            \
        ap_.x = pk2(a0r[s_].x, a0r[s_].y); ap_.y = pk2(a0r[s_].z, a0r[s_].w); \
        ap_.z = pk2(a1r[s_].x, a1r[s_].y); ap_.w = pk2(a1r[s_].z, a1r[s_].w); \
        *(uint4*)(As + (b_) * 2560 + ar * 40 + ac) = ap_;                     \
        uint4 bp_;                                                            \
        bp_.x = pk2(br[s_][0], br[s_][1]); bp_.y = pk2(br[s_][2], br[s_][3]); \
        bp_.z = pk2(br[s_][4], br[s_][5]); bp_.w = pk2(br[s_][6], br[s_][7]); \
        *(uint4*)(Bs + (b_) * 2560 + bn * 40 + bk0) = bp_;                    \
    } while (0)

    QLOAD(0, 0);
    QPACK(0, 0);
    QLOAD(1, 1);
    LGKM_BARRIER();

#pragma unroll
    for (int it = 0; it < 16; ++it) {
        if (it < 14) QLOAD(it & 1, it + 2);

        const unsigned short* Ab = As + (it & 1) * 2560;
        const unsigned short* Bb = Bs + (it & 1) * 2560;
        short8 fa0 = *(const short8*)(Ab + (wr + l16) * 40 + quad * 8);
        short8 fa1 = *(const short8*)(Ab + (wr + 16 + l16) * 40 + quad * 8);
        short8 fb0 = *(const short8*)(Bb + (wc + l16) * 40 + quad * 8);
        short8 fb1 = *(const short8*)(Bb + (wc + 16 + l16) * 40 + quad * 8);
        acc00 = __builtin_amdgcn_mfma_f32_16x16x32_bf16(fa0, fb0, acc00, 0, 0, 0);
        acc01 = __builtin_amdgcn_mfma_f32_16x16x32_bf16(fa0, fb1, acc01, 0, 0, 0);
        acc10 = __builtin_amdgcn_mfma_f32_16x16x32_bf16(fa1, fb0, acc10, 0, 0, 0);
        acc11 = __builtin_amdgcn_mfma_f32_16x16x32_bf16(fa1, fb1, acc11, 0, 0, 0);

        if (it < 15) {
            QPACK((it + 1) & 1, (it + 1) & 1);
            LGKM_BARRIER();
        }
    }
#undef QLOAD
#undef QPACK

    if (active) {
#pragma unroll
        for (int mi = 0; mi < 2; ++mi) {
#pragma unroll
            for (int ni = 0; ni < 2; ++ni) {
                f32x4 a = (mi == 0) ? ((ni == 0) ? acc00 : acc01)
                                    : ((ni == 0) ? acc10 : acc11);
                int n = n0 + wc + ni * 16 + l16;
                float bval = bias[n];
#pragma unroll
                for (int r = 0; r < 4; ++r) {
                    int m = m0 + wr + mi * 16 + quad * 4 + r;
                    C[(size_t)m * E_DIM + n] = (a[r] + bval) * scale;
                }
            }
        }
    }
}

// ---------------------------------------------------------------------------
// Fused cooperative kernel: 256 blocks x 512 thr, 1 block/CU (108 KB LDS).
// Stage A: qkv (768 tile-units over 512 half-blocks, 2 uniform iterations)
// Stage B: scores + edge-softmax + diffusion step 1 (512 units, 1/half)
// Stage C: diffusion steps 2-5 banded MFMA (256 units, 1/block)
// Stage D: h5 @ Wo + bo + x + LN (128 units, blocks 0..127)
// grid.sync() between stages (cooperative launch; harness-supported).
// ---------------------------------------------------------------------------
__global__ __launch_bounds__(512, 1)
void fused_all(const float* __restrict__ x, const float* __restrict__ amask,
               const float* __restrict__ Wq, const float* __restrict__ bq,
               const float* __restrict__ Wk, const float* __restrict__ bk,
               const float* __restrict__ Wv, const float* __restrict__ bv,
               const float* __restrict__ Wo, const float* __restrict__ bo,
               const float* __restrict__ lng, const float* __restrict__ lnb,
               float* __restrict__ out,
               float* __restrict__ q, float* __restrict__ k, float* __restrict__ v,
               float* __restrict__ P, float* __restrict__ hA,
               unsigned short* __restrict__ h5b)
{
    __shared__ __align__(16) unsigned char smem[110592];
    cg::grid_group grid = cg::this_grid();

    const int tid  = threadIdx.x;
    const int bid  = blockIdx.x;
    const int half = tid >> 8;
    const int htid = tid & 255;
    const int lane = tid & 63, wave = tid >> 6;
    const int quad = lane >> 4, l16 = lane & 15;

    // ================= Stage A: qkv =================
    {
        unsigned short* As = (unsigned short*)(smem + half * 20480);
        unsigned short* Bs = As + 2 * 2560;
#pragma unroll
        for (int it = 0; it < 2; ++it) {
            int u = it * 512 + bid * 2 + half;
            bool active = (u < 768);
            int uc = active ? u : 767;
            int z  = uc >> 8;
            int mt = (uc >> 3) & 31;
            int nt = uc & 7;
            const float* W; const float* b; float* o; float sc;
            if (z == 0)      { W = Wq; b = bq; o = q; sc = 0.125f; }
            else if (z == 1) { W = Wk; b = bk; o = k; sc = 1.0f; }
            else             { W = Wv; b = bv; o = v; sc = 1.0f; }
            gemm64(x, W, b, o, sc, mt * 64, nt * 64, As, Bs, htid, active);
        }
    }
    __threadfence();
    grid.sync();

    // ================= Stage B: scores + softmax + step 1 =================
    {
        unsigned char* hb = smem + half * 34816;
        float* ks = (float*)hb;                 // 96*68*4 = 26112
        float* am = (float*)(hb + 26112);       // 384
        float* ps = (float*)(hb + 26496);       // 32*65*4 = 8320
        int u = bid * 2 + half;                 // 0..511
        const int i0 = (u >> 3) * 32;
        const int h  = u & 7;

        for (int e = htid; e < 96 * 16; e += 256) {
            int lr = e >> 4, c4 = e & 15;
            int j = i0 - WH + lr;
            int jc = min(max(j, 0), S_LEN - 1);
            *(float4*)(ks + lr * 68 + c4 * 4) =
                *(const float4*)(k + (size_t)jc * E_DIM + h * 64 + c4 * 4);
        }
        if (htid < 96) {
            int j = i0 - WH + htid;
            am[htid] = (j >= 0 && j < S_LEN) ? amask[j] : -1.0f;
        }

        const int dst = htid >> 3;
        const int og  = htid & 7;
        float4 qreg[16];
        {
            const float4* qrow = (const float4*)(q + (size_t)(i0 + dst) * E_DIM + h * 64);
#pragma unroll
            for (int t = 0; t < 16; ++t) qreg[t] = qrow[t];
        }
        __syncthreads();                        // S1

        float sreg[9];
#pragma unroll
        for (int t = 0; t < 9; ++t) sreg[t] = -INFINITY;
#pragma unroll
        for (int t = 0; t < 9; ++t) {
            int off = og + 8 * t;
            if (off > 64) break;
            int j = i0 + dst + off - WH;
            if (j >= 0 && j < S_LEN) {
                int lr = dst + off;
                const float4* kr = (const float4*)(ks + lr * 68);
                float acc = 0.f;
#pragma unroll
                for (int uu = 0; uu < 16; ++uu) {
                    float4 a = qreg[uu], bb = kr[uu];
                    acc += a.x * bb.x + a.y * bb.y + a.z * bb.z + a.w * bb.w;
                }
                sreg[t] = (am[lr] >= 0.f) ? acc : -1e9f;
            }
        }
        __syncthreads();                        // S2: k reads done

        for (int e = htid; e < 96 * 16; e += 256) {
            int lr = e >> 4, c4 = e & 15;
            int j = i0 - WH + lr;
            int jc = min(max(j, 0), S_LEN - 1);
            *(float4*)(ks + lr * 68 + c4 * 4) =
                *(const float4*)(v + (size_t)jc * E_DIM + h * 64 + c4 * 4);
        }

        float mx = sreg[0];
#pragma unroll
        for (int t = 1; t < 9; ++t) mx = fmaxf(mx, sreg[t]);
#pragma unroll
        for (int o = 1; o < 8; o <<= 1) mx = fmaxf(mx, __shfl_xor(mx, o, 64));
        float dn = 0.f;
#pragma unroll
        for (int t = 0; t < 9; ++t) {
            sreg[t] = expf(sreg[t] - mx);
            dn += sreg[t];
        }
#pragma unroll
        for (int o = 1; o < 8; o <<= 1) dn += __shfl_xor(dn, o, 64);
        float rinv = 1.f / dn;
#pragma unroll
        for (int t = 0; t < 9; ++t) {
            int off = og + 8 * t;
            if (off > 64) break;
            float pv = sreg[t] * rinv;
            P[(size_t)(i0 + dst) * PROW + h * NOFF + off] = pv;
            ps[dst * NOFF + off] = pv;
        }
        __syncthreads();                        // S3: ps + v staged

        {
            const int ci = htid & 15;
            const int ob = (htid >> 4) * 2;
            float4 a0 = {0,0,0,0}, a1 = a0;
            for (int lr = ob; lr < ob + 66; ++lr) {
                float4 hval = *(const float4*)(ks + lr * 68 + ci * 4);
                int o0 = lr - ob;
                if (o0 <= 64) {
                    float p = ps[ob * NOFF + o0];
                    a0.x += p * hval.x; a0.y += p * hval.y; a0.z += p * hval.z; a0.w += p * hval.w;
                }
                int o1 = o0 - 1;
                if ((unsigned)o1 <= 64u) {
                    float p = ps[(ob + 1) * NOFF + o1];
                    a1.x += p * hval.x; a1.y += p * hval.y; a1.z += p * hval.z; a1.w += p * hval.w;
                }
            }
#pragma unroll
            for (int r = 0; r < 2; ++r) {
                float4 a = r ? a1 : a0;
                float4 vv = *(const float4*)(ks + (WH + ob + r) * 68 + ci * 4);
                float4 o;
                o.x = 0.9f * a.x + 0.1f * vv.x;
                o.y = 0.9f * a.y + 0.1f * vv.y;
                o.z = 0.9f * a.z + 0.1f * vv.z;
                o.w = 0.9f * a.w + 0.1f * vv.w;
                *(float4*)(hA + (size_t)(i0 + ob + r) * E_DIM + h * 64 + ci * 4) = o;
            }
        }
    }
    __threadfence();
    grid.sync();

    // ================= Stage C: diffusion steps 2-5 (banded MFMA) =========
    {
        unsigned short* inT = (unsigned short*)smem;            // 64*328 u16
        unsigned short* m1T = (unsigned short*)(smem + 41984);  // 64*264 u16
        unsigned short* ps  = (unsigned short*)(smem + 75776);  // 256*66 u16
        unsigned short* m2T = inT;                              // stride 200
        unsigned short* m3T = m1T;                              // stride 136
        const int i0 = (bid >> 3) * 64;
        const int h  = bid & 7;
        const int c0 = h * 64;

        for (int e = tid; e < 160 * 16; e += 512) {
            int rp = (e >> 4) * 2, c4 = (e & 15) * 4;
            int ja = min(max(i0 - 128 + rp,     0), S_LEN - 1);
            int jb = min(max(i0 - 128 + rp + 1, 0), S_LEN - 1);
            float4 ha = *(const float4*)(hA + (size_t)ja * E_DIM + c0 + c4);
            float4 hb2 = *(const float4*)(hA + (size_t)jb * E_DIM + c0 + c4);
            *(unsigned*)(inT + (c4 + 0) * 328 + rp) = pk2(ha.x, hb2.x);
            *(unsigned*)(inT + (c4 + 1) * 328 + rp) = pk2(ha.y, hb2.y);
            *(unsigned*)(inT + (c4 + 2) * 328 + rp) = pk2(ha.z, hb2.z);
            *(unsigned*)(inT + (c4 + 3) * 328 + rp) = pk2(ha.w, hb2.w);
        }
        for (int e = tid; e < 256 * 33; e += 512) {
            int mr = e / 33, t = e - mr * 33;
            int jc = min(max(i0 - 96 + mr, 0), S_LEN - 1);
            const float* pr = P + (size_t)jc * PROW + h * NOFF;
            if (t < 32)
                *(unsigned*)(ps + mr * 66 + t * 2) = pk2(pr[t * 2], pr[t * 2 + 1]);
            else
                ps[mr * 66 + 64] = f2bf(pr[64]);
        }
        __syncthreads();

        // s1: h2 rows (0..255), inT -> m1T
#pragma unroll
        for (int uu = 0; uu < 4; ++uu) {
            int u = wave + uu * 8;
            int mtb = (u >> 1) * 16;
            int ntb = (u & 1) * 32;
            f32x4 a0 = {0.f,0.f,0.f,0.f}, a1 = a0;
            int ks0 = mtb >> 5;
            const int m = mtb + l16;
#pragma unroll
            for (int t = 0; t < 3; ++t) {
                int k0q = (ks0 + t) * 32 + quad * 8;
                short8 fa;
#pragma unroll
                for (int j = 0; j < 8; ++j) {
                    int idx = k0q + j - m;
                    int idc = min(max(idx, 0), 64);
                    unsigned short pv = ps[m * 66 + idc];
                    fa[j] = ((unsigned)idx <= 64u) ? (short)pv : (short)0;
                }
                short8 fb0 = *(const short8*)(inT + (ntb + l16) * 328 + k0q);
                short8 fb1 = *(const short8*)(inT + (ntb + 16 + l16) * 328 + k0q);
                a0 = __builtin_amdgcn_mfma_f32_16x16x32_bf16(fa, fb0, a0, 0, 0, 0);
                a1 = __builtin_amdgcn_mfma_f32_16x16x32_bf16(fa, fb1, a1, 0, 0, 0);
            }
#pragma unroll
            for (int nt = 0; nt < 2; ++nt) {
                f32x4 a = nt ? a1 : a0;
                int n = ntb + nt * 16 + l16;
                float o[4];
#pragma unroll
                for (int r = 0; r < 4; ++r) {
                    int gm = min(max(i0 - 96 + mtb + quad * 4 + r, 0), S_LEN - 1);
                    o[r] = 0.9f * a[r] + 0.1f * v[(size_t)gm * E_DIM + c0 + n];
                }
                *(unsigned*)(m1T + n * 264 + mtb + quad * 4)     = pk2(o[0], o[1]);
                *(unsigned*)(m1T + n * 264 + mtb + quad * 4 + 2) = pk2(o[2], o[3]);
            }
        }
        __syncthreads();

        // s2: h3 rows (0..191), m1T -> m2T (overlays inT)
#pragma unroll
        for (int uu = 0; uu < 3; ++uu) {
            int u = wave + uu * 8;
            int mtb = (u >> 1) * 16;
            int ntb = (u & 1) * 32;
            f32x4 a0 = {0.f,0.f,0.f,0.f}, a1 = a0;
            int ks0 = mtb >> 5;
            const int m = mtb + l16;
#pragma unroll
            for (int t = 0; t < 3; ++t) {
                int k0q = (ks0 + t) * 32 + quad * 8;
                short8 fa;
#pragma unroll
                for (int j = 0; j < 8; ++j) {
                    int idx = k0q + j - m;
                    int idc = min(max(idx, 0), 64);
                    unsigned short pv = ps[(m + 32) * 66 + idc];
                    fa[j] = ((unsigned)idx <= 64u) ? (short)pv : (short)0;
                }
                short8 fb0 = *(const short8*)(m1T + (ntb + l16) * 264 + k0q);
                short8 fb1 = *(const short8*)(m1T + (ntb + 16 + l16) * 264 + k0q);
                a0 = __builtin_amdgcn_mfma_f32_16x16x32_bf16(fa, fb0, a0, 0, 0, 0);
                a1 = __builtin_amdgcn_mfma_f32_16x16x32_bf16(fa, fb1, a1, 0, 0, 0);
            }
#pragma unroll
            for (int nt = 0; nt < 2; ++nt) {
                f32x4 a = nt ? a1 : a0;
                int n = ntb + nt * 16 + l16;
                float o[4];
#pragma unroll
                for (int r = 0; r < 4; ++r) {
                    int gm = min(max(i0 - 64 + mtb + quad * 4 + r, 0), S_LEN - 1);
                    o[r] = 0.9f * a[r] + 0.1f * v[(size_t)gm * E_DIM + c0 + n];
                }
                *(unsigned*)(m2T + n * 200 + mtb + quad * 4)     = pk2(o[0], o[1]);
                *(unsigned*)(m2T + n * 200 + mtb + quad * 4 + 2) = pk2(o[2], o[3]);
            }
        }
        __syncthreads();

        // s3: h4 rows (0..127), m2T -> m3T (overlays m1T)
#pragma unroll
        for (int uu = 0; uu < 2; ++uu) {
            int u = wave + uu * 8;
            int mtb = (u >> 1) * 16;
            int ntb = (u & 1) * 32;
            f32x4 a0 = {0.f,0.f,0.f,0.f}, a1 = a0;
            int ks0 = mtb >> 5;
            const int m = mtb + l16;
#pragma unroll
            for (int t = 0; t < 3; ++t) {
                int k0q = (ks0 + t) * 32 + quad * 8;
                short8 fa;
#pragma unroll
                for (int j = 0; j < 8; ++j) {
                    int idx = k0q + j - m;
                    int idc = min(max(idx, 0), 64);
                    unsigned short pv = ps[(m + 64) * 66 + idc];
                    fa[j] = ((unsigned)idx <= 64u) ? (short)pv : (short)0;
                }
                short8 fb0 = *(const short8*)(m2T + (ntb + l16) * 200 + k0q);
                short8 fb1 = *(const short8*)(m2T + (ntb + 16 + l16) * 200 + k0q);
                a0 = __builtin_amdgcn_mfma_f32_16x16x32_bf16(fa, fb0, a0, 0, 0, 0);
                a1 = __builtin_amdgcn_mfma_f32_16x16x32_bf16(fa, fb1, a1, 0, 0, 0);
            }
#pragma unroll
            for (int nt = 0; nt < 2; ++nt) {
                f32x4 a = nt ? a1 : a0;
                int n = ntb + nt * 16 + l16;
                float o[4];
#pragma unroll
                for (int r = 0; r < 4; ++r) {
                    int gm = min(max(i0 - 32 + mtb + quad * 4 + r, 0), S_LEN - 1);
                    o[r] = 0.9f * a[r] + 0.1f * v[(size_t)gm * E_DIM + c0 + n];
                }
                *(unsigned*)(m3T + n * 136 + mtb + quad * 4)     = pk2(o[0], o[1]);
                *(unsigned*)(m3T + n * 136 + mtb + quad * 4 + 2) = pk2(o[2], o[3]);
            }
        }
        __syncthreads();

        // s4: h5 rows (0..63) -> global bf16
        {
            int u = wave;
            int mtb = (u >> 1) * 16;
            int ntb = (u & 1) * 32;
            f32x4 a0 = {0.f,0.f,0.f,0.f}, a1 = a0;
            int ks0 = mtb >> 5;
            const int m = mtb + l16;
#pragma unroll
            for (int t = 0; t < 3; ++t) {
                int k0q = (ks0 + t) * 32 + quad * 8;
                short8 fa;
#pragma unroll
                for (int j = 0; j < 8; ++j) {
                    int idx = k0q + j - m;
                    int idc = min(max(idx, 0), 64);
                    unsigned short pv = ps[(m + 96) * 66 + idc];
                    fa[j] = ((unsigned)idx <= 64u) ? (short)pv : (short)0;
                }
                short8 fb0 = *(const short8*)(m3T + (ntb + l16) * 136 + k0q);
                short8 fb1 = *(const short8*)(m3T + (ntb + 16 + l16) * 136 + k0q);
                a0 = __builtin_amdgcn_mfma_f32_16x16x32_bf16(fa, fb0, a0, 0, 0, 0);
                a1 = __builtin_amdgcn_mfma_f32_16x16x32_bf16(fa, fb1, a1, 0, 0, 0);
            }
#pragma unroll
            for (int nt = 0; nt < 2; ++nt) {
                f32x4 a = nt ? a1 : a0;
                int n = ntb + nt * 16 + l16;
#pragma unroll
                for (int r = 0; r < 4; ++r) {
                    int gm = i0 + mtb + quad * 4 + r;
                    float vv = v[(size_t)gm * E_DIM + c0 + n];
                    h5b[(size_t)gm * E_DIM + c0 + n] = f2bf(0.9f * a[r] + 0.1f * vv);
                }
            }
        }
    }
    __threadfence();
    grid.sync();

    // ================= Stage D: h5 @ Wo + bo + x + LayerNorm ==============
    if (bid < 128) {
        unsigned short* Bs2 = (unsigned short*)smem;            // 2 x 512*40 u16
        float* rsum = (float*)(smem + 81920);                   // 8*16 f32
        float* rsq  = (float*)(smem + 81920 + 512);
        const int m0 = bid * 16;
        const int n = tid;

        short8 far_[16];
#pragma unroll
        for (int t = 0; t < 16; ++t)
            far_[t] = *(const short8*)(h5b + (size_t)(m0 + l16) * E_DIM + t * 32 + quad * 8);

        {
            float w0[32];
#pragma unroll
            for (int j = 0; j < 32; ++j)
                w0[j] = Wo[(size_t)j * E_DIM + n];
#pragma unroll
            for (int t = 0; t < 4; ++t) {
                uint4 bp;
                bp.x = pk2(w0[t*8+0], w0[t*8+1]); bp.y = pk2(w0[t*8+2], w0[t*8+3]);
                bp.z = pk2(w0[t*8+4], w0[t*8+5]); bp.w = pk2(w0[t*8+6], w0[t*8+7]);
                *(uint4*)(Bs2 + n * 40 + t * 8) = bp;
            }
        }
        LGKM_BARRIER();

        f32x4 acc[4];
#pragma unroll
        for (int t = 0; t < 4; ++t) acc[t] = (f32x4){0.f,0.f,0.f,0.f};

#pragma unroll
        for (int it = 0; it < 16; ++it) {
            float wn[32];
            if (it < 15) {
#pragma unroll
                for (int j = 0; j < 32; ++j)
                    wn[j] = Wo[(size_t)((it + 1) * 32 + j) * E_DIM + n];
            }

#pragma unroll
            for (int nt = 0; nt < 4; ++nt) {
                short8 fb = *(const short8*)(Bs2 + (it & 1) * 20480 +
                                             (wave * 64 + nt * 16 + l16) * 40 + quad * 8);
                acc[nt] = __builtin_amdgcn_mfma_f32_16x16x32_bf16(far_[it], fb, acc[nt], 0, 0, 0);
            }

            if (it < 15) {
#pragma unroll
                for (int t = 0; t < 4; ++t) {
                    uint4 bp;
                    bp.x = pk2(wn[t*8+0], wn[t*8+1]); bp.y = pk2(wn[t*8+2], wn[t*8+3]);
                    bp.z = pk2(wn[t*8+4], wn[t*8+5]); bp.w = pk2(wn[t*8+6], wn[t*8+7]);
                    *(uint4*)(Bs2 + ((it + 1) & 1) * 20480 + n * 40 + t * 8) = bp;
                }
                LGKM_BARRIER();
            }
        }

        float s[4] = {0.f,0.f,0.f,0.f}, s2[4] = {0.f,0.f,0.f,0.f};
#pragma unroll
        for (int nt = 0; nt < 4; ++nt) {
            int nc = wave * 64 + nt * 16 + l16;
            float bv = bo[nc];
#pragma unroll
            for (int r = 0; r < 4; ++r) {
                int m = m0 + quad * 4 + r;
                float vl = acc[nt][r] + bv + x[(size_t)m * E_DIM + nc];
                acc[nt][r] = vl;
                s[r] += vl; s2[r] += vl * vl;
            }
        }
#pragma unroll
        for (int o = 1; o < 16; o <<= 1) {
#pragma unroll
            for (int r = 0; r < 4; ++r) {
                s[r]  += __shfl_xor(s[r], o, 64);
                s2[r] += __shfl_xor(s2[r], o, 64);
            }
        }
        if (l16 == 0) {
#pragma unroll
            for (int r = 0; r < 4; ++r) {
                rsum[wave * 16 + quad * 4 + r] = s[r];
                rsq[wave * 16 + quad * 4 + r]  = s2[r];
            }
        }
        __syncthreads();
        float mu[4], rs[4];
#pragma unroll
        for (int r = 0; r < 4; ++r) {
            int rl = quad * 4 + r;
            float tot = 0.f, tot2 = 0.f;
#pragma unroll
            for (int w = 0; w < 8; ++w) { tot += rsum[w * 16 + rl]; tot2 += rsq[w * 16 + rl]; }
            float m_ = tot * (1.f / 512.f);
            float var = tot2 * (1.f / 512.f) - m_ * m_;
            mu[r] = m_; rs[r] = rsqrtf(var + 1e-12f);
        }
#pragma unroll
        for (int nt = 0; nt < 4; ++nt) {
            int nc = wave * 64 + nt * 16 + l16;
            float gv = lng[nc], bbv = lnb[nc];
#pragma unroll
            for (int r = 0; r < 4; ++r) {
                int m = m0 + quad * 4 + r;
                out[(size_t)m * E_DIM + nc] = (acc[nt][r] - mu[r]) * rs[r] * gv + bbv;
            }
        }
    }
}

// ---------------------------------------------------------------------------
extern "C" void kernel_launch(void* const* d_in, const int* in_sizes, int n_in,
                              void* d_out, int out_size, void* d_ws, size_t ws_size,
                              hipStream_t stream)
{
    const float* x     = (const float*)d_in[0];
    const float* amask = (const float*)d_in[1];
    const float* Wq = (const float*)d_in[4];
    const float* bq = (const float*)d_in[5];
    const float* Wk = (const float*)d_in[6];
    const float* bk = (const float*)d_in[7];
    const float* Wv = (const float*)d_in[8];
    const float* bv = (const float*)d_in[9];
    const float* Wo = (const float*)d_in[10];
    const float* bo = (const float*)d_in[11];
    const float* lng = (const float*)d_in[12];
    const float* lnb = (const float*)d_in[13];
    float* out = (float*)d_out;

    float* ws = (float*)d_ws;
    float* q  = ws;
    float* k  = ws + (size_t)NE;
    float* v  = ws + (size_t)2 * NE;
    float* P  = ws + (size_t)3 * NE;
    float* hA = ws + (size_t)3 * NE + PN;
    unsigned short* h5b = (unsigned short*)(ws + (size_t)4 * NE + PN);

    void* kargs[] = {
        (void*)&x, (void*)&amask,
        (void*)&Wq, (void*)&bq, (void*)&Wk, (void*)&bk, (void*)&Wv, (void*)&bv,
        (void*)&Wo, (void*)&bo, (void*)&lng, (void*)&lnb,
        (void*)&out,
        (void*)&q, (void*)&k, (void*)&v, (void*)&P, (void*)&hA, (void*)&h5b
    };
    hipLaunchCooperativeKernel((const void*)fused_all, dim3(256), dim3(512),
                               kargs, 0, stream);
}

// Round 5
// 300.929 us; speedup vs baseline: 1.4201x; 1.4201x over previous
//
#include <hip/hip_runtime.h>
#include <math.h>

#define S_LEN 2048
#define E_DIM 512
#define NE (S_LEN * E_DIM)
#define H_NUM 8
#define WH 32
#define NOFF 65
#define PROW (H_NUM * NOFF) /* 520 */
#define PN (S_LEN * PROW)
#define NBLK 256

typedef float f32x4 __attribute__((ext_vector_type(4)));
typedef short short8 __attribute__((ext_vector_type(8)));

__device__ __forceinline__ unsigned short f2bf(float f) {
    union { float f; unsigned u; } cv; cv.f = f;
    unsigned u = cv.u;
    u += 0x7fffu + ((u >> 16) & 1u);   // RNE
    return (unsigned short)(u >> 16);
}
__device__ __forceinline__ unsigned pk2(float x, float y) {
    return (unsigned)f2bf(x) | ((unsigned)f2bf(y) << 16);
}

// Raw barrier: lgkmcnt(0) only, no vmcnt drain (T3/T4 minimum form).
#define LGKM_BARRIER() do {                                   \
    __builtin_amdgcn_sched_barrier(0);                        \
    asm volatile("s_waitcnt lgkmcnt(0)" ::: "memory");        \
    __builtin_amdgcn_s_barrier();                             \
    __builtin_amdgcn_sched_barrier(0);                        \
} while (0)

// ---------------------------------------------------------------------------
// Hand-rolled grid barrier (replaces cg::grid_group::sync(), which profiled
// at ~80us/sync in R4: fused_all 331us with only 8% VALUBusy).
// Sense-reversing: cnt counts arrivals (self-resets each phase BEFORE the
// gen release, so it is 0 at kernel exit -> safe across graph replays);
// spinners poll gen (read-not-assumed, so poison-resilient) with s_sleep.
// Agent-scope atomics; release fence before arrive, acquire after pass
// (cross-XCD L2 non-coherence, G16).
// ---------------------------------------------------------------------------
__device__ __forceinline__ void grid_barrier(unsigned* cnt, unsigned* gen) {
    __syncthreads();
    if (threadIdx.x == 0) {
        __threadfence();   // release our stage's global writes
        unsigned g = __hip_atomic_load(gen, __ATOMIC_RELAXED, __HIP_MEMORY_SCOPE_AGENT);
        unsigned prev = __hip_atomic_fetch_add(cnt, 1u, __ATOMIC_ACQ_REL, __HIP_MEMORY_SCOPE_AGENT);
        if (prev == NBLK - 1u) {
            __hip_atomic_store(cnt, 0u, __ATOMIC_RELAXED, __HIP_MEMORY_SCOPE_AGENT);
            __hip_atomic_store(gen, g + 1u, __ATOMIC_RELEASE, __HIP_MEMORY_SCOPE_AGENT);
        } else {
            while (__hip_atomic_load(gen, __ATOMIC_RELAXED, __HIP_MEMORY_SCOPE_AGENT) == g)
                __builtin_amdgcn_s_sleep(4);
        }
        __threadfence();   // acquire: invalidate this CU's L1 / XCD L2
    }
    __syncthreads();
}

// ---------------------------------------------------------------------------
// Stage A helper (proven qkv core, parameterized LDS + half-block tid).
// ---------------------------------------------------------------------------
__device__ __forceinline__ void gemm64(
    const float* __restrict__ A, const float* __restrict__ W,
    const float* __restrict__ bias, float* __restrict__ C,
    float scale, int m0, int n0,
    unsigned short* As, unsigned short* Bs, int htid, bool active)
{
    const int lane = htid & 63;
    const int wave = (htid >> 6) & 3;
    const int quad = lane >> 4, l16 = lane & 15;
    const int wr = (wave >> 1) * 32, wc = (wave & 1) * 32;
    const int ar = htid >> 2, ac = (htid & 3) * 8;
    const int bn = htid & 63, bk0 = ((htid >> 6) & 3) * 8;

    f32x4 acc00 = {0.f,0.f,0.f,0.f}, acc01 = acc00, acc10 = acc00, acc11 = acc00;

    const float* Arow = A + (size_t)(m0 + ar) * E_DIM;

    float4 a0r[2], a1r[2];
    float  br[2][8];

#define QLOAD(s_, i_) do {                                                    \
        int kk_ = (i_) * 32;                                                  \
        a0r[s_] = *(const float4*)(Arow + kk_ + ac);                          \
        a1r[s_] = *(const float4*)(Arow + kk_ + ac + 4);                      \
        _Pragma("unroll")                                                     \
        for (int j_ = 0; j_ < 8; ++j_)                                        \
            br[s_][j_] = W[(size_t)(kk_ + bk0 + j_) * E_DIM + n0 + bn];       \
    } while (0)

#define QPACK(s_, b_) do {                                                    \
        uint4 ap_;                                                            \
        ap_.x = pk2(a0r[s_].x, a0r[s_].y); ap_.y = pk2(a0r[s_].z, a0r[s_].w); \
        ap_.z = pk2(a1r[s_].x, a1r[s_].y); ap_.w = pk2(a1r[s_].z, a1r[s_].w); \
        *(uint4*)(As + (b_) * 2560 + ar * 40 + ac) = ap_;                     \
        uint4 bp_;                                                            \
        bp_.x = pk2(br[s_][0], br[s_][1]); bp_.y = pk2(br[s_][2], br[s_][3]); \
        bp_.z = pk2(br[s_][4], br[s_][5]); bp_.w = pk2(br[s_][6], br[s_][7]); \
        *(uint4*)(Bs + (b_) * 2560 + bn * 40 + bk0) = bp_;                    \
    } while (0)

    QLOAD(0, 0);
    QPACK(0, 0);
    QLOAD(1, 1);
    LGKM_BARRIER();

#pragma unroll
    for (int it = 0; it < 16; ++it) {
        if (it < 14) QLOAD(it & 1, it + 2);

        const unsigned short* Ab = As + (it & 1) * 2560;
        const unsigned short* Bb = Bs + (it & 1) * 2560;
        short8 fa0 = *(const short8*)(Ab + (wr + l16) * 40 + quad * 8);
        short8 fa1 = *(const short8*)(Ab + (wr + 16 + l16) * 40 + quad * 8);
        short8 fb0 = *(const short8*)(Bb + (wc + l16) * 40 + quad * 8);
        short8 fb1 = *(const short8*)(Bb + (wc + 16 + l16) * 40 + quad * 8);
        acc00 = __builtin_amdgcn_mfma_f32_16x16x32_bf16(fa0, fb0, acc00, 0, 0, 0);
        acc01 = __builtin_amdgcn_mfma_f32_16x16x32_bf16(fa0, fb1, acc01, 0, 0, 0);
        acc10 = __builtin_amdgcn_mfma_f32_16x16x32_bf16(fa1, fb0, acc10, 0, 0, 0);
        acc11 = __builtin_amdgcn_mfma_f32_16x16x32_bf16(fa1, fb1, acc11, 0, 0, 0);

        if (it < 15) {
            QPACK((it + 1) & 1, (it + 1) & 1);
            LGKM_BARRIER();
        }
    }
#undef QLOAD
#undef QPACK

    if (active) {
#pragma unroll
        for (int mi = 0; mi < 2; ++mi) {
#pragma unroll
            for (int ni = 0; ni < 2; ++ni) {
                f32x4 a = (mi == 0) ? ((ni == 0) ? acc00 : acc01)
                                    : ((ni == 0) ? acc10 : acc11);
                int n = n0 + wc + ni * 16 + l16;
                float bval = bias[n];
#pragma unroll
                for (int r = 0; r < 4; ++r) {
                    int m = m0 + wr + mi * 16 + quad * 4 + r;
                    C[(size_t)m * E_DIM + n] = (a[r] + bval) * scale;
                }
            }
        }
    }
}

// ---------------------------------------------------------------------------
// Fused cooperative kernel: 256 blocks x 512 thr, 1 block/CU (108 KB LDS).
// Custom grid_barrier between stages (R5: replaces slow cg grid.sync).
// ---------------------------------------------------------------------------
__global__ __launch_bounds__(512, 1)
void fused_all(const float* __restrict__ x, const float* __restrict__ amask,
               const float* __restrict__ Wq, const float* __restrict__ bq,
               const float* __restrict__ Wk, const float* __restrict__ bk,
               const float* __restrict__ Wv, const float* __restrict__ bv,
               const float* __restrict__ Wo, const float* __restrict__ bo,
               const float* __restrict__ lng, const float* __restrict__ lnb,
               float* __restrict__ out,
               float* __restrict__ q, float* __restrict__ k, float* __restrict__ v,
               float* __restrict__ P, float* __restrict__ hA,
               unsigned short* __restrict__ h5b,
               unsigned* __restrict__ bar_cnt, unsigned* __restrict__ bar_gen)
{
    __shared__ __align__(16) unsigned char smem[110592];

    const int tid  = threadIdx.x;
    const int bid  = blockIdx.x;
    const int half = tid >> 8;
    const int htid = tid & 255;
    const int lane = tid & 63, wave = tid >> 6;
    const int quad = lane >> 4, l16 = lane & 15;

    // ================= Stage A: qkv =================
    {
        unsigned short* As = (unsigned short*)(smem + half * 20480);
        unsigned short* Bs = As + 2 * 2560;
#pragma unroll
        for (int it = 0; it < 2; ++it) {
            int u = it * 512 + bid * 2 + half;
            bool active = (u < 768);
            int uc = active ? u : 767;
            int z  = uc >> 8;
            int mt = (uc >> 3) & 31;
            int nt = uc & 7;
            const float* W; const float* b; float* o; float sc;
            if (z == 0)      { W = Wq; b = bq; o = q; sc = 0.125f; }
            else if (z == 1) { W = Wk; b = bk; o = k; sc = 1.0f; }
            else             { W = Wv; b = bv; o = v; sc = 1.0f; }
            gemm64(x, W, b, o, sc, mt * 64, nt * 64, As, Bs, htid, active);
        }
    }
    grid_barrier(bar_cnt, bar_gen);

    // ================= Stage B: scores + softmax + step 1 =================
    {
        unsigned char* hb = smem + half * 34816;
        float* ks = (float*)hb;                 // 96*68*4 = 26112
        float* am = (float*)(hb + 26112);       // 384
        float* ps = (float*)(hb + 26496);       // 32*65*4 = 8320
        int u = bid * 2 + half;                 // 0..511
        const int i0 = (u >> 3) * 32;
        const int h  = u & 7;

        for (int e = htid; e < 96 * 16; e += 256) {
            int lr = e >> 4, c4 = e & 15;
            int j = i0 - WH + lr;
            int jc = min(max(j, 0), S_LEN - 1);
            *(float4*)(ks + lr * 68 + c4 * 4) =
                *(const float4*)(k + (size_t)jc * E_DIM + h * 64 + c4 * 4);
        }
        if (htid < 96) {
            int j = i0 - WH + htid;
            am[htid] = (j >= 0 && j < S_LEN) ? amask[j] : -1.0f;
        }

        const int dst = htid >> 3;
        const int og  = htid & 7;
        float4 qreg[16];
        {
            const float4* qrow = (const float4*)(q + (size_t)(i0 + dst) * E_DIM + h * 64);
#pragma unroll
            for (int t = 0; t < 16; ++t) qreg[t] = qrow[t];
        }
        __syncthreads();                        // S1

        float sreg[9];
#pragma unroll
        for (int t = 0; t < 9; ++t) sreg[t] = -INFINITY;
#pragma unroll
        for (int t = 0; t < 9; ++t) {
            int off = og + 8 * t;
            if (off > 64) break;
            int j = i0 + dst + off - WH;
            if (j >= 0 && j < S_LEN) {
                int lr = dst + off;
                const float4* kr = (const float4*)(ks + lr * 68);
                float acc = 0.f;
#pragma unroll
                for (int uu = 0; uu < 16; ++uu) {
                    float4 a = qreg[uu], bb = kr[uu];
                    acc += a.x * bb.x + a.y * bb.y + a.z * bb.z + a.w * bb.w;
                }
                sreg[t] = (am[lr] >= 0.f) ? acc : -1e9f;
            }
        }
        __syncthreads();                        // S2: k reads done

        for (int e = htid; e < 96 * 16; e += 256) {
            int lr = e >> 4, c4 = e & 15;
            int j = i0 - WH + lr;
            int jc = min(max(j, 0), S_LEN - 1);
            *(float4*)(ks + lr * 68 + c4 * 4) =
                *(const float4*)(v + (size_t)jc * E_DIM + h * 64 + c4 * 4);
        }

        float mx = sreg[0];
#pragma unroll
        for (int t = 1; t < 9; ++t) mx = fmaxf(mx, sreg[t]);
#pragma unroll
        for (int o = 1; o < 8; o <<= 1) mx = fmaxf(mx, __shfl_xor(mx, o, 64));
        float dn = 0.f;
#pragma unroll
        for (int t = 0; t < 9; ++t) {
            sreg[t] = expf(sreg[t] - mx);
            dn += sreg[t];
        }
#pragma unroll
        for (int o = 1; o < 8; o <<= 1) dn += __shfl_xor(dn, o, 64);
        float rinv = 1.f / dn;
#pragma unroll
        for (int t = 0; t < 9; ++t) {
            int off = og + 8 * t;
            if (off > 64) break;
            float pv = sreg[t] * rinv;
            P[(size_t)(i0 + dst) * PROW + h * NOFF + off] = pv;
            ps[dst * NOFF + off] = pv;
        }
        __syncthreads();                        // S3: ps + v staged

        {
            const int ci = htid & 15;
            const int ob = (htid >> 4) * 2;
            float4 a0 = {0,0,0,0}, a1 = a0;
            for (int lr = ob; lr < ob + 66; ++lr) {
                float4 hval = *(const float4*)(ks + lr * 68 + ci * 4);
                int o0 = lr - ob;
                if (o0 <= 64) {
                    float p = ps[ob * NOFF + o0];
                    a0.x += p * hval.x; a0.y += p * hval.y; a0.z += p * hval.z; a0.w += p * hval.w;
                }
                int o1 = o0 - 1;
                if ((unsigned)o1 <= 64u) {
                    float p = ps[(ob + 1) * NOFF + o1];
                    a1.x += p * hval.x; a1.y += p * hval.y; a1.z += p * hval.z; a1.w += p * hval.w;
                }
            }
#pragma unroll
            for (int r = 0; r < 2; ++r) {
                float4 a = r ? a1 : a0;
                float4 vv = *(const float4*)(ks + (WH + ob + r) * 68 + ci * 4);
                float4 o;
                o.x = 0.9f * a.x + 0.1f * vv.x;
                o.y = 0.9f * a.y + 0.1f * vv.y;
                o.z = 0.9f * a.z + 0.1f * vv.z;
                o.w = 0.9f * a.w + 0.1f * vv.w;
                *(float4*)(hA + (size_t)(i0 + ob + r) * E_DIM + h * 64 + ci * 4) = o;
            }
        }
    }
    grid_barrier(bar_cnt, bar_gen);

    // ================= Stage C: diffusion steps 2-5 (banded MFMA) =========
    {
        unsigned short* inT = (unsigned short*)smem;            // 64*328 u16
        unsigned short* m1T = (unsigned short*)(smem + 41984);  // 64*264 u16
        unsigned short* ps  = (unsigned short*)(smem + 75776);  // 256*66 u16
        unsigned short* m2T = inT;                              // stride 200
        unsigned short* m3T = m1T;                              // stride 136
        const int i0 = (bid >> 3) * 64;
        const int h  = bid & 7;
        const int c0 = h * 64;

        for (int e = tid; e < 160 * 16; e += 512) {
            int rp = (e >> 4) * 2, c4 = (e & 15) * 4;
            int ja = min(max(i0 - 128 + rp,     0), S_LEN - 1);
            int jb = min(max(i0 - 128 + rp + 1, 0), S_LEN - 1);
            float4 ha = *(const float4*)(hA + (size_t)ja * E_DIM + c0 + c4);
            float4 hb2 = *(const float4*)(hA + (size_t)jb * E_DIM + c0 + c4);
            *(unsigned*)(inT + (c4 + 0) * 328 + rp) = pk2(ha.x, hb2.x);
            *(unsigned*)(inT + (c4 + 1) * 328 + rp) = pk2(ha.y, hb2.y);
            *(unsigned*)(inT + (c4 + 2) * 328 + rp) = pk2(ha.z, hb2.z);
            *(unsigned*)(inT + (c4 + 3) * 328 + rp) = pk2(ha.w, hb2.w);
        }
        for (int e = tid; e < 256 * 33; e += 512) {
            int mr = e / 33, t = e - mr * 33;
            int jc = min(max(i0 - 96 + mr, 0), S_LEN - 1);
            const float* pr = P + (size_t)jc * PROW + h * NOFF;
            if (t < 32)
                *(unsigned*)(ps + mr * 66 + t * 2) = pk2(pr[t * 2], pr[t * 2 + 1]);
            else
                ps[mr * 66 + 64] = f2bf(pr[64]);
        }
        __syncthreads();

        // s1: h2 rows (0..255), inT -> m1T
#pragma unroll
        for (int uu = 0; uu < 4; ++uu) {
            int u = wave + uu * 8;
            int mtb = (u >> 1) * 16;
            int ntb = (u & 1) * 32;
            f32x4 a0 = {0.f,0.f,0.f,0.f}, a1 = a0;
            int ks0 = mtb >> 5;
            const int m = mtb + l16;
#pragma unroll
            for (int t = 0; t < 3; ++t) {
                int k0q = (ks0 + t) * 32 + quad * 8;
                short8 fa;
#pragma unroll
                for (int j = 0; j < 8; ++j) {
                    int idx = k0q + j - m;
                    int idc = min(max(idx, 0), 64);
                    unsigned short pv = ps[m * 66 + idc];
                    fa[j] = ((unsigned)idx <= 64u) ? (short)pv : (short)0;
                }
                short8 fb0 = *(const short8*)(inT + (ntb + l16) * 328 + k0q);
                short8 fb1 = *(const short8*)(inT + (ntb + 16 + l16) * 328 + k0q);
                a0 = __builtin_amdgcn_mfma_f32_16x16x32_bf16(fa, fb0, a0, 0, 0, 0);
                a1 = __builtin_amdgcn_mfma_f32_16x16x32_bf16(fa, fb1, a1, 0, 0, 0);
            }
#pragma unroll
            for (int nt = 0; nt < 2; ++nt) {
                f32x4 a = nt ? a1 : a0;
                int n = ntb + nt * 16 + l16;
                float o[4];
#pragma unroll
                for (int r = 0; r < 4; ++r) {
                    int gm = min(max(i0 - 96 + mtb + quad * 4 + r, 0), S_LEN - 1);
                    o[r] = 0.9f * a[r] + 0.1f * v[(size_t)gm * E_DIM + c0 + n];
                }
                *(unsigned*)(m1T + n * 264 + mtb + quad * 4)     = pk2(o[0], o[1]);
                *(unsigned*)(m1T + n * 264 + mtb + quad * 4 + 2) = pk2(o[2], o[3]);
            }
        }
        __syncthreads();

        // s2: h3 rows (0..191), m1T -> m2T (overlays inT)
#pragma unroll
        for (int uu = 0; uu < 3; ++uu) {
            int u = wave + uu * 8;
            int mtb = (u >> 1) * 16;
            int ntb = (u & 1) * 32;
            f32x4 a0 = {0.f,0.f,0.f,0.f}, a1 = a0;
            int ks0 = mtb >> 5;
            const int m = mtb + l16;
#pragma unroll
            for (int t = 0; t < 3; ++t) {
                int k0q = (ks0 + t) * 32 + quad * 8;
                short8 fa;
#pragma unroll
                for (int j = 0; j < 8; ++j) {
                    int idx = k0q + j - m;
                    int idc = min(max(idx, 0), 64);
                    unsigned short pv = ps[(m + 32) * 66 + idc];
                    fa[j] = ((unsigned)idx <= 64u) ? (short)pv : (short)0;
                }
                short8 fb0 = *(const short8*)(m1T + (ntb + l16) * 264 + k0q);
                short8 fb1 = *(const short8*)(m1T + (ntb + 16 + l16) * 264 + k0q);
                a0 = __builtin_amdgcn_mfma_f32_16x16x32_bf16(fa, fb0, a0, 0, 0, 0);
                a1 = __builtin_amdgcn_mfma_f32_16x16x32_bf16(fa, fb1, a1, 0, 0, 0);
            }
#pragma unroll
            for (int nt = 0; nt < 2; ++nt) {
                f32x4 a = nt ? a1 : a0;
                int n = ntb + nt * 16 + l16;
                float o[4];
#pragma unroll
                for (int r = 0; r < 4; ++r) {
                    int gm = min(max(i0 - 64 + mtb + quad * 4 + r, 0), S_LEN - 1);
                    o[r] = 0.9f * a[r] + 0.1f * v[(size_t)gm * E_DIM + c0 + n];
                }
                *(unsigned*)(m2T + n * 200 + mtb + quad * 4)     = pk2(o[0], o[1]);
                *(unsigned*)(m2T + n * 200 + mtb + quad * 4 + 2) = pk2(o[2], o[3]);
            }
        }
        __syncthreads();

        // s3: h4 rows (0..127), m2T -> m3T (overlays m1T)
#pragma unroll
        for (int uu = 0; uu < 2; ++uu) {
            int u = wave + uu * 8;
            int mtb = (u >> 1) * 16;
            int ntb = (u & 1) * 32;
            f32x4 a0 = {0.f,0.f,0.f,0.f}, a1 = a0;
            int ks0 = mtb >> 5;
            const int m = mtb + l16;
#pragma unroll
            for (int t = 0; t < 3; ++t) {
                int k0q = (ks0 + t) * 32 + quad * 8;
                short8 fa;
#pragma unroll
                for (int j = 0; j < 8; ++j) {
                    int idx = k0q + j - m;
                    int idc = min(max(idx, 0), 64);
                    unsigned short pv = ps[(m + 64) * 66 + idc];
                    fa[j] = ((unsigned)idx <= 64u) ? (short)pv : (short)0;
                }
                short8 fb0 = *(const short8*)(m2T + (ntb + l16) * 200 + k0q);
                short8 fb1 = *(const short8*)(m2T + (ntb + 16 + l16) * 200 + k0q);
                a0 = __builtin_amdgcn_mfma_f32_16x16x32_bf16(fa, fb0, a0, 0, 0, 0);
                a1 = __builtin_amdgcn_mfma_f32_16x16x32_bf16(fa, fb1, a1, 0, 0, 0);
            }
#pragma unroll
            for (int nt = 0; nt < 2; ++nt) {
                f32x4 a = nt ? a1 : a0;
                int n = ntb + nt * 16 + l16;
                float o[4];
#pragma unroll
                for (int r = 0; r < 4; ++r) {
                    int gm = min(max(i0 - 32 + mtb + quad * 4 + r, 0), S_LEN - 1);
                    o[r] = 0.9f * a[r] + 0.1f * v[(size_t)gm * E_DIM + c0 + n];
                }
                *(unsigned*)(m3T + n * 136 + mtb + quad * 4)     = pk2(o[0], o[1]);
                *(unsigned*)(m3T + n * 136 + mtb + quad * 4 + 2) = pk2(o[2], o[3]);
            }
        }
        __syncthreads();

        // s4: h5 rows (0..63) -> global bf16
        {
            int u = wave;
            int mtb = (u >> 1) * 16;
            int ntb = (u & 1) * 32;
            f32x4 a0 = {0.f,0.f,0.f,0.f}, a1 = a0;
            int ks0 = mtb >> 5;
            const int m = mtb + l16;
#pragma unroll
            for (int t = 0; t < 3; ++t) {
                int k0q = (ks0 + t) * 32 + quad * 8;
                short8 fa;
#pragma unroll
                for (int j = 0; j < 8; ++j) {
                    int idx = k0q + j - m;
                    int idc = min(max(idx, 0), 64);
                    unsigned short pv = ps[(m + 96) * 66 + idc];
                    fa[j] = ((unsigned)idx <= 64u) ? (short)pv : (short)0;
                }
                short8 fb0 = *(const short8*)(m3T + (ntb + l16) * 136 + k0q);
                short8 fb1 = *(const short8*)(m3T + (ntb + 16 + l16) * 136 + k0q);
                a0 = __builtin_amdgcn_mfma_f32_16x16x32_bf16(fa, fb0, a0, 0, 0, 0);
                a1 = __builtin_amdgcn_mfma_f32_16x16x32_bf16(fa, fb1, a1, 0, 0, 0);
            }
#pragma unroll
            for (int nt = 0; nt < 2; ++nt) {
                f32x4 a = nt ? a1 : a0;
                int n = ntb + nt * 16 + l16;
#pragma unroll
                for (int r = 0; r < 4; ++r) {
                    int gm = i0 + mtb + quad * 4 + r;
                    float vv = v[(size_t)gm * E_DIM + c0 + n];
                    h5b[(size_t)gm * E_DIM + c0 + n] = f2bf(0.9f * a[r] + 0.1f * vv);
                }
            }
        }
    }
    grid_barrier(bar_cnt, bar_gen);

    // ================= Stage D: h5 @ Wo + bo + x + LayerNorm ==============
    if (bid < 128) {
        unsigned short* Bs2 = (unsigned short*)smem;            // 2 x 512*40 u16
        float* rsum = (float*)(smem + 81920);                   // 8*16 f32
        float* rsq  = (float*)(smem + 81920 + 512);
        const int m0 = bid * 16;
        const int n = tid;

        short8 far_[16];
#pragma unroll
        for (int t = 0; t < 16; ++t)
            far_[t] = *(const short8*)(h5b + (size_t)(m0 + l16) * E_DIM + t * 32 + quad * 8);

        {
            float w0[32];
#pragma unroll
            for (int j = 0; j < 32; ++j)
                w0[j] = Wo[(size_t)j * E_DIM + n];
#pragma unroll
            for (int t = 0; t < 4; ++t) {
                uint4 bp;
                bp.x = pk2(w0[t*8+0], w0[t*8+1]); bp.y = pk2(w0[t*8+2], w0[t*8+3]);
                bp.z = pk2(w0[t*8+4], w0[t*8+5]); bp.w = pk2(w0[t*8+6], w0[t*8+7]);
                *(uint4*)(Bs2 + n * 40 + t * 8) = bp;
            }
        }
        LGKM_BARRIER();

        f32x4 acc[4];
#pragma unroll
        for (int t = 0; t < 4; ++t) acc[t] = (f32x4){0.f,0.f,0.f,0.f};

#pragma unroll
        for (int it = 0; it < 16; ++it) {
            float wn[32];
            if (it < 15) {
#pragma unroll
                for (int j = 0; j < 32; ++j)
                    wn[j] = Wo[(size_t)((it + 1) * 32 + j) * E_DIM + n];
            }

#pragma unroll
            for (int nt = 0; nt < 4; ++nt) {
                short8 fb = *(const short8*)(Bs2 + (it & 1) * 20480 +
                                             (wave * 64 + nt * 16 + l16) * 40 + quad * 8);
                acc[nt] = __builtin_amdgcn_mfma_f32_16x16x32_bf16(far_[it], fb, acc[nt], 0, 0, 0);
            }

            if (it < 15) {
#pragma unroll
                for (int t = 0; t < 4; ++t) {
                    uint4 bp;
                    bp.x = pk2(wn[t*8+0], wn[t*8+1]); bp.y = pk2(wn[t*8+2], wn[t*8+3]);
                    bp.z = pk2(wn[t*8+4], wn[t*8+5]); bp.w = pk2(wn[t*8+6], wn[t*8+7]);
                    *(uint4*)(Bs2 + ((it + 1) & 1) * 20480 + n * 40 + t * 8) = bp;
                }
                LGKM_BARRIER();
            }
        }

        float s[4] = {0.f,0.f,0.f,0.f}, s2[4] = {0.f,0.f,0.f,0.f};
#pragma unroll
        for (int nt = 0; nt < 4; ++nt) {
            int nc = wave * 64 + nt * 16 + l16;
            float bv = bo[nc];
#pragma unroll
            for (int r = 0; r < 4; ++r) {
                int m = m0 + quad * 4 + r;
                float vl = acc[nt][r] + bv + x[(size_t)m * E_DIM + nc];
                acc[nt][r] = vl;
                s[r] += vl; s2[r] += vl * vl;
            }
        }
#pragma unroll
        for (int o = 1; o < 16; o <<= 1) {
#pragma unroll
            for (int r = 0; r < 4; ++r) {
                s[r]  += __shfl_xor(s[r], o, 64);
                s2[r] += __shfl_xor(s2[r], o, 64);
            }
        }
        if (l16 == 0) {
#pragma unroll
            for (int r = 0; r < 4; ++r) {
                rsum[wave * 16 + quad * 4 + r] = s[r];
                rsq[wave * 16 + quad * 4 + r]  = s2[r];
            }
        }
        __syncthreads();
        float mu[4], rs[4];
#pragma unroll
        for (int r = 0; r < 4; ++r) {
            int rl = quad * 4 + r;
            float tot = 0.f, tot2 = 0.f;
#pragma unroll
            for (int w = 0; w < 8; ++w) { tot += rsum[w * 16 + rl]; tot2 += rsq[w * 16 + rl]; }
            float m_ = tot * (1.f / 512.f);
            float var = tot2 * (1.f / 512.f) - m_ * m_;
            mu[r] = m_; rs[r] = rsqrtf(var + 1e-12f);
        }
#pragma unroll
        for (int nt = 0; nt < 4; ++nt) {
            int nc = wave * 64 + nt * 16 + l16;
            float gv = lng[nc], bbv = lnb[nc];
#pragma unroll
            for (int r = 0; r < 4; ++r) {
                int m = m0 + quad * 4 + r;
                out[(size_t)m * E_DIM + nc] = (acc[nt][r] - mu[r]) * rs[r] * gv + bbv;
            }
        }
    }
}

// ---------------------------------------------------------------------------
extern "C" void kernel_launch(void* const* d_in, const int* in_sizes, int n_in,
                              void* d_out, int out_size, void* d_ws, size_t ws_size,
                              hipStream_t stream)
{
    const float* x     = (const float*)d_in[0];
    const float* amask = (const float*)d_in[1];
    const float* Wq = (const float*)d_in[4];
    const float* bq = (const float*)d_in[5];
    const float* Wk = (const float*)d_in[6];
    const float* bk = (const float*)d_in[7];
    const float* Wv = (const float*)d_in[8];
    const float* bv = (const float*)d_in[9];
    const float* Wo = (const float*)d_in[10];
    const float* bo = (const float*)d_in[11];
    const float* lng = (const float*)d_in[12];
    const float* lnb = (const float*)d_in[13];
    float* out = (float*)d_out;

    float* ws = (float*)d_ws;
    float* q  = ws;
    float* k  = ws + (size_t)NE;
    float* v  = ws + (size_t)2 * NE;
    float* P  = ws + (size_t)3 * NE;
    float* hA = ws + (size_t)3 * NE + PN;
    unsigned short* h5b = (unsigned short*)(ws + (size_t)4 * NE + PN);
    // barrier vars far from all used intermediates (usage ~23MB; ws is 268MB)
    unsigned* bar = (unsigned*)(ws + (size_t)8 * 1024 * 1024);

    hipMemsetAsync((void*)bar, 0, 2 * sizeof(unsigned), stream);

    unsigned* bar_cnt = bar;
    unsigned* bar_gen = bar + 1;

    void* kargs[] = {
        (void*)&x, (void*)&amask,
        (void*)&Wq, (void*)&bq, (void*)&Wk, (void*)&bk, (void*)&Wv, (void*)&bv,
        (void*)&Wo, (void*)&bo, (void*)&lng, (void*)&lnb,
        (void*)&out,
        (void*)&q, (void*)&k, (void*)&v, (void*)&P, (void*)&hA, (void*)&h5b,
        (void*)&bar_cnt, (void*)&bar_gen
    };
    hipLaunchCooperativeKernel((const void*)fused_all, dim3(256), dim3(512),
                               kargs, 0, stream);
}

// Round 6
// 155.108 us; speedup vs baseline: 2.7551x; 1.9401x over previous
//
#include <hip/hip_runtime.h>
#include <math.h>

#define S_LEN 2048
#define E_DIM 512
#define NE (S_LEN * E_DIM)
#define H_NUM 8
#define WH 32
#define NOFF 65
#define PROW (H_NUM * NOFF) /* 520 */
#define PN (S_LEN * PROW)

typedef float f32x4 __attribute__((ext_vector_type(4)));
typedef short short8 __attribute__((ext_vector_type(8)));

__device__ __forceinline__ unsigned short f2bf(float f) {
    union { float f; unsigned u; } cv; cv.f = f;
    unsigned u = cv.u;
    u += 0x7fffu + ((u >> 16) & 1u);   // RNE
    return (unsigned short)(u >> 16);
}
__device__ __forceinline__ unsigned pk2(float x, float y) {
    return (unsigned)f2bf(x) | ((unsigned)f2bf(y) << 16);
}

// Raw barrier: lgkmcnt(0) only, no vmcnt drain (T3/T4 minimum form).
#define LGKM_BARRIER() do {                                   \
    __builtin_amdgcn_sched_barrier(0);                        \
    asm volatile("s_waitcnt lgkmcnt(0)" ::: "memory");        \
    __builtin_amdgcn_s_barrier();                             \
    __builtin_amdgcn_sched_barrier(0);                        \
} while (0)

// ---------------------------------------------------------------------------
// qkv (proven R2-r2, unchanged): C = (x@W + bias)*scale, 64x64 tiles,
// dbuf LDS, loads 2 iters ahead, one lgkm-only barrier per k-step.
// ---------------------------------------------------------------------------
__device__ __forceinline__ void mfma_gemm_f32(
    const float* __restrict__ A, const float* __restrict__ W,
    const float* __restrict__ bias, float* __restrict__ C,
    float scale, int m0, int n0)
{
    __shared__ unsigned short As[2][64 * 40];
    __shared__ unsigned short Bs[2][64 * 40];
    const int tid = threadIdx.x;
    const int lane = tid & 63, wave = tid >> 6;
    const int quad = lane >> 4, l16 = lane & 15;
    const int wr = (wave >> 1) * 32, wc = (wave & 1) * 32;
    const int ar = tid >> 2, ac = (tid & 3) * 8;
    const int bn = tid & 63, bk0 = (tid >> 6) * 8;

    f32x4 acc00 = {0.f,0.f,0.f,0.f}, acc01 = acc00, acc10 = acc00, acc11 = acc00;

    const float* Arow = A + (size_t)(m0 + ar) * E_DIM;

    float4 a0r[2], a1r[2];
    float  br[2][8];

#define QLOAD(s_, i_) do {                                                    \
        int kk_ = (i_) * 32;                                                  \
        a0r[s_] = *(const float4*)(Arow + kk_ + ac);                          \
        a1r[s_] = *(const float4*)(Arow + kk_ + ac + 4);                      \
        _Pragma("unroll")                                                     \
        for (int j_ = 0; j_ < 8; ++j_)                                        \
            br[s_][j_] = W[(size_t)(kk_ + bk0 + j_) * E_DIM + n0 + bn];       \
    } while (0)

#define QPACK(s_, b_) do {                                                    \
        uint4 ap_;                                                            \
        ap_.x = pk2(a0r[s_].x, a0r[s_].y); ap_.y = pk2(a0r[s_].z, a0r[s_].w); \
        ap_.z = pk2(a1r[s_].x, a1r[s_].y); ap_.w = pk2(a1r[s_].z, a1r[s_].w); \
        *(uint4*)(&As[b_][0] + ar * 40 + ac) = ap_;                           \
        uint4 bp_;                                                            \
        bp_.x = pk2(br[s_][0], br[s_][1]); bp_.y = pk2(br[s_][2], br[s_][3]); \
        bp_.z = pk2(br[s_][4], br[s_][5]); bp_.w = pk2(br[s_][6], br[s_][7]); \
        *(uint4*)(&Bs[b_][0] + bn * 40 + bk0) = bp_;                          \
    } while (0)

    QLOAD(0, 0);
    QPACK(0, 0);
    QLOAD(1, 1);
    LGKM_BARRIER();

#pragma unroll
    for (int it = 0; it < 16; ++it) {
        if (it < 14) QLOAD(it & 1, it + 2);

        const unsigned short* Ab = &As[it & 1][0];
        const unsigned short* Bb = &Bs[it & 1][0];
        short8 fa0 = *(const short8*)(Ab + (wr + l16) * 40 + quad * 8);
        short8 fa1 = *(const short8*)(Ab + (wr + 16 + l16) * 40 + quad * 8);
        short8 fb0 = *(const short8*)(Bb + (wc + l16) * 40 + quad * 8);
        short8 fb1 = *(const short8*)(Bb + (wc + 16 + l16) * 40 + quad * 8);
        acc00 = __builtin_amdgcn_mfma_f32_16x16x32_bf16(fa0, fb0, acc00, 0, 0, 0);
        acc01 = __builtin_amdgcn_mfma_f32_16x16x32_bf16(fa0, fb1, acc01, 0, 0, 0);
        acc10 = __builtin_amdgcn_mfma_f32_16x16x32_bf16(fa1, fb0, acc10, 0, 0, 0);
        acc11 = __builtin_amdgcn_mfma_f32_16x16x32_bf16(fa1, fb1, acc11, 0, 0, 0);

        if (it < 15) {
            QPACK((it + 1) & 1, (it + 1) & 1);
            LGKM_BARRIER();
        }
    }
#undef QLOAD
#undef QPACK

#pragma unroll
    for (int mi = 0; mi < 2; ++mi) {
#pragma unroll
        for (int ni = 0; ni < 2; ++ni) {
            f32x4 a = (mi == 0) ? ((ni == 0) ? acc00 : acc01)
                                : ((ni == 0) ? acc10 : acc11);
            int n = n0 + wc + ni * 16 + l16;
            float bval = bias[n];
#pragma unroll
            for (int r = 0; r < 4; ++r) {
                int m = m0 + wr + mi * 16 + quad * 4 + r;
                C[(size_t)m * E_DIM + n] = (a[r] + bval) * scale;
            }
        }
    }
}

__global__ __launch_bounds__(256)
void qkv_gemm(const float* __restrict__ x,
              const float* __restrict__ Wq, const float* __restrict__ bq,
              const float* __restrict__ Wk, const float* __restrict__ bk,
              const float* __restrict__ Wv, const float* __restrict__ bv,
              float* __restrict__ q, float* __restrict__ k, float* __restrict__ v)
{
    const float* W; const float* b; float* o; float sc;
    if (blockIdx.z == 0)      { W = Wq; b = bq; o = q; sc = 0.125f; }
    else if (blockIdx.z == 1) { W = Wk; b = bk; o = k; sc = 1.0f; }
    else                      { W = Wv; b = bv; o = v; sc = 1.0f; }
    mfma_gemm_f32(x, W, b, o, sc, blockIdx.y * 64, blockIdx.x * 64);
}

// ---------------------------------------------------------------------------
// scores_d1 (R6: P and hA now stored bf16 -- both were consumed only after
// an identical f2bf conversion downstream, so results are bit-identical).
// ---------------------------------------------------------------------------
#define SDN 32
__global__ __launch_bounds__(256)
void scores_d1(const float* __restrict__ q, const float* __restrict__ k,
               const float* __restrict__ v, const float* __restrict__ amask,
               unsigned short* __restrict__ Pb, unsigned short* __restrict__ hAb)
{
    const int i0 = blockIdx.x * SDN;
    const int h  = blockIdx.y;
    const int tid = threadIdx.x;
    __shared__ float ks[96 * 68];      // k rows [i0-32,i0+64); later v rows
    __shared__ float am[96];
    __shared__ float ps[SDN * NOFF];

    for (int e = tid; e < 96 * 16; e += 256) {
        int lr = e >> 4, c4 = e & 15;
        int j = i0 - WH + lr;
        int jc = min(max(j, 0), S_LEN - 1);
        *(float4*)(ks + lr * 68 + c4 * 4) =
            *(const float4*)(k + (size_t)jc * E_DIM + h * 64 + c4 * 4);
    }
    if (tid < 96) {
        int j = i0 - WH + tid;
        am[tid] = (j >= 0 && j < S_LEN) ? amask[j] : -1.0f;
    }

    const int dst = tid >> 3;
    const int og  = tid & 7;
    float4 qreg[16];
    {
        const float4* qrow = (const float4*)(q + (size_t)(i0 + dst) * E_DIM + h * 64);
#pragma unroll
        for (int t = 0; t < 16; ++t) qreg[t] = qrow[t];
    }
    __syncthreads();

    float sreg[9];
#pragma unroll
    for (int t = 0; t < 9; ++t) sreg[t] = -INFINITY;
#pragma unroll
    for (int t = 0; t < 9; ++t) {
        int off = og + 8 * t;
        if (off > 64) break;
        int j = i0 + dst + off - WH;
        if (j >= 0 && j < S_LEN) {
            int lr = dst + off;
            const float4* kr = (const float4*)(ks + lr * 68);
            float acc = 0.f;
#pragma unroll
            for (int u = 0; u < 16; ++u) {
                float4 a = qreg[u], bb = kr[u];
                acc += a.x * bb.x + a.y * bb.y + a.z * bb.z + a.w * bb.w;
            }
            sreg[t] = (am[lr] >= 0.f) ? acc : -1e9f;
        }
    }
    __syncthreads();

    for (int e = tid; e < 96 * 16; e += 256) {
        int lr = e >> 4, c4 = e & 15;
        int j = i0 - WH + lr;
        int jc = min(max(j, 0), S_LEN - 1);
        *(float4*)(ks + lr * 68 + c4 * 4) =
            *(const float4*)(v + (size_t)jc * E_DIM + h * 64 + c4 * 4);
    }

    float mx = sreg[0];
#pragma unroll
    for (int t = 1; t < 9; ++t) mx = fmaxf(mx, sreg[t]);
#pragma unroll
    for (int o = 1; o < 8; o <<= 1) mx = fmaxf(mx, __shfl_xor(mx, o, 64));
    float dn = 0.f;
#pragma unroll
    for (int t = 0; t < 9; ++t) {
        sreg[t] = expf(sreg[t] - mx);
        dn += sreg[t];
    }
#pragma unroll
    for (int o = 1; o < 8; o <<= 1) dn += __shfl_xor(dn, o, 64);
    float rinv = 1.f / dn;
#pragma unroll
    for (int t = 0; t < 9; ++t) {
        int off = og + 8 * t;
        if (off > 64) break;
        float pv = sreg[t] * rinv;
        Pb[(size_t)(i0 + dst) * PROW + h * NOFF + off] = f2bf(pv);
        ps[dst * NOFF + off] = pv;
    }
    __syncthreads();

    {
        const int ci = tid & 15;
        const int ob = (tid >> 4) * 2;
        float4 a0 = {0,0,0,0}, a1 = a0;
        for (int lr = ob; lr < ob + 66; ++lr) {
            float4 hval = *(const float4*)(ks + lr * 68 + ci * 4);
            int o0 = lr - ob;
            if (o0 <= 64) {
                float p = ps[ob * NOFF + o0];
                a0.x += p * hval.x; a0.y += p * hval.y; a0.z += p * hval.z; a0.w += p * hval.w;
            }
            int o1 = o0 - 1;
            if ((unsigned)o1 <= 64u) {
                float p = ps[(ob + 1) * NOFF + o1];
                a1.x += p * hval.x; a1.y += p * hval.y; a1.z += p * hval.z; a1.w += p * hval.w;
            }
        }
#pragma unroll
        for (int r = 0; r < 2; ++r) {
            float4 a = r ? a1 : a0;
            float4 vv = *(const float4*)(ks + (WH + ob + r) * 68 + ci * 4);
            ushort4 o4;
            o4.x = f2bf(0.9f * a.x + 0.1f * vv.x);
            o4.y = f2bf(0.9f * a.y + 0.1f * vv.y);
            o4.z = f2bf(0.9f * a.z + 0.1f * vv.z);
            o4.w = f2bf(0.9f * a.w + 0.1f * vv.w);
            *(ushort4*)(hAb + (size_t)(i0 + ob + r) * E_DIM + h * 64 + ci * 4) = o4;
        }
    }
}

// ---------------------------------------------------------------------------
// diffuse4m (R6): steps 2-5 banded MFMA. Band matrix now staged into a
// ZERO-PADDED, PER-ROW-SHIFTED layout ps2[256][136]:
//   ps2[r][32 + (r&7) + o] = P[r][o],  o in [0,64]; zeros elsewhere.
// The (r&7) shift makes every short8 band read 16B-aligned
// (byte = 272r + 64 - 16*(r/8) + 2*roff + 2*k0q, all multiples of 16), so
// the fa fragment becomes ONE ds_read_b128 instead of 8 scalar reads +
// clamp + select (240 scalar reads/thread -> 30 b128 reads/thread).
// hA and P inputs are bf16 (identical f2bf numerics as before).
// LDS: inT 41984 + m1T 33792 + ps2 69632 = 145408 B (1 block/CU, as before).
// ---------------------------------------------------------------------------
__global__ __launch_bounds__(512)
void diffuse4m(const unsigned short* __restrict__ hAb, const float* __restrict__ v,
               const unsigned short* __restrict__ Pb, unsigned short* __restrict__ h5b)
{
    __shared__ unsigned short inT[64 * 328];  // h1: 320 rows [i0-128,i0+192)
    __shared__ unsigned short m1T[64 * 264];  // h2: 256 rows [i0-96,i0+160)
    __shared__ unsigned short ps2[256 * 136]; // padded/shifted band rows
    unsigned short* m2T = inT;                // h3: 192 rows, stride 200
    unsigned short* m3T = m1T;                // h4: 128 rows, stride 136
    const int i0 = blockIdx.x * 64;
    const int h  = blockIdx.y;
    const int c0 = h * 64;
    const int tid  = threadIdx.x;
    const int lane = tid & 63, wave = tid >> 6;
    const int quad = lane >> 4, l16 = lane & 15;

    // zero ps2 (pass 1)
    for (int e = tid; e < 256 * 68; e += 512)
        ((unsigned*)ps2)[e] = 0u;

    // stage h1 (320 rows, bf16 source) -> inT transposed
    for (int e = tid; e < 160 * 16; e += 512) {
        int rp = (e >> 4) * 2, c4 = (e & 15) * 4;
        int ja = min(max(i0 - 128 + rp,     0), S_LEN - 1);
        int jb = min(max(i0 - 128 + rp + 1, 0), S_LEN - 1);
        ushort4 ha = *(const ushort4*)(hAb + (size_t)ja * E_DIM + c0 + c4);
        ushort4 hb = *(const ushort4*)(hAb + (size_t)jb * E_DIM + c0 + c4);
        *(unsigned*)(inT + (c4 + 0) * 328 + rp) = (unsigned)ha.x | ((unsigned)hb.x << 16);
        *(unsigned*)(inT + (c4 + 1) * 328 + rp) = (unsigned)ha.y | ((unsigned)hb.y << 16);
        *(unsigned*)(inT + (c4 + 2) * 328 + rp) = (unsigned)ha.z | ((unsigned)hb.z << 16);
        *(unsigned*)(inT + (c4 + 3) * 328 + rp) = (unsigned)ha.w | ((unsigned)hb.w << 16);
    }
    __syncthreads();   // zeros visible before band fill overwrites

    // band fill (pass 2): wave w handles rows w, w+8, ...
    for (int it = 0; it < 32; ++it) {
        int row = wave + it * 8;
        int jc = min(max(i0 - 96 + row, 0), S_LEN - 1);
        const unsigned short* src = Pb + (size_t)jc * PROW + h * NOFF;
        unsigned short* dst = ps2 + row * 136 + 32 + (row & 7);
        dst[lane] = src[lane];
        if (lane == 0) dst[64] = src[64];
    }
    __syncthreads();

#define BAND_FA(roff_)                                                        \
    *(const short8*)(ps2 + (size_t)(m + (roff_)) * 136 + 32 +                 \
                     ((m + (roff_)) & 7) + (k0q - m))

    // ---- s1: h2 rows (0..255), inT -> m1T. roff 0.
#pragma unroll
    for (int uu = 0; uu < 4; ++uu) {
        int u = wave + uu * 8;
        int mtb = (u >> 1) * 16;
        int ntb = (u & 1) * 32;
        f32x4 a0 = {0.f,0.f,0.f,0.f}, a1 = a0;
        int ks0 = mtb >> 5;
        const int m = mtb + l16;
#pragma unroll
        for (int t = 0; t < 3; ++t) {
            int k0q = (ks0 + t) * 32 + quad * 8;
            short8 fa = BAND_FA(0);
            short8 fb0 = *(const short8*)(inT + (ntb + l16) * 328 + k0q);
            short8 fb1 = *(const short8*)(inT + (ntb + 16 + l16) * 328 + k0q);
            a0 = __builtin_amdgcn_mfma_f32_16x16x32_bf16(fa, fb0, a0, 0, 0, 0);
            a1 = __builtin_amdgcn_mfma_f32_16x16x32_bf16(fa, fb1, a1, 0, 0, 0);
        }
#pragma unroll
        for (int nt = 0; nt < 2; ++nt) {
            f32x4 a = nt ? a1 : a0;
            int n = ntb + nt * 16 + l16;
            float o[4];
#pragma unroll
            for (int r = 0; r < 4; ++r) {
                int gm = min(max(i0 - 96 + mtb + quad * 4 + r, 0), S_LEN - 1);
                o[r] = 0.9f * a[r] + 0.1f * v[(size_t)gm * E_DIM + c0 + n];
            }
            *(unsigned*)(m1T + n * 264 + mtb + quad * 4)     = pk2(o[0], o[1]);
            *(unsigned*)(m1T + n * 264 + mtb + quad * 4 + 2) = pk2(o[2], o[3]);
        }
    }
    __syncthreads();   // inT reads done -> m2T overlay safe; m1T visible

    // ---- s2: h3 rows (0..191), m1T -> m2T. roff 32.
#pragma unroll
    for (int uu = 0; uu < 3; ++uu) {
        int u = wave + uu * 8;
        int mtb = (u >> 1) * 16;
        int ntb = (u & 1) * 32;
        f32x4 a0 = {0.f,0.f,0.f,0.f}, a1 = a0;
        int ks0 = mtb >> 5;
        const int m = mtb + l16;
#pragma unroll
        for (int t = 0; t < 3; ++t) {
            int k0q = (ks0 + t) * 32 + quad * 8;
            short8 fa = BAND_FA(32);
            short8 fb0 = *(const short8*)(m1T + (ntb + l16) * 264 + k0q);
            short8 fb1 = *(const short8*)(m1T + (ntb + 16 + l16) * 264 + k0q);
            a0 = __builtin_amdgcn_mfma_f32_16x16x32_bf16(fa, fb0, a0, 0, 0, 0);
            a1 = __builtin_amdgcn_mfma_f32_16x16x32_bf16(fa, fb1, a1, 0, 0, 0);
        }
#pragma unroll
        for (int nt = 0; nt < 2; ++nt) {
            f32x4 a = nt ? a1 : a0;
            int n = ntb + nt * 16 + l16;
            float o[4];
#pragma unroll
            for (int r = 0; r < 4; ++r) {
                int gm = min(max(i0 - 64 + mtb + quad * 4 + r, 0), S_LEN - 1);
                o[r] = 0.9f * a[r] + 0.1f * v[(size_t)gm * E_DIM + c0 + n];
            }
            *(unsigned*)(m2T + n * 200 + mtb + quad * 4)     = pk2(o[0], o[1]);
            *(unsigned*)(m2T + n * 200 + mtb + quad * 4 + 2) = pk2(o[2], o[3]);
        }
    }
    __syncthreads();   // m1T reads done -> m3T overlay safe; m2T visible

    // ---- s3: h4 rows (0..127), m2T -> m3T. roff 64.
#pragma unroll
    for (int uu = 0; uu < 2; ++uu) {
        int u = wave + uu * 8;
        int mtb = (u >> 1) * 16;
        int ntb = (u & 1) * 32;
        f32x4 a0 = {0.f,0.f,0.f,0.f}, a1 = a0;
        int ks0 = mtb >> 5;
        const int m = mtb + l16;
#pragma unroll
        for (int t = 0; t < 3; ++t) {
            int k0q = (ks0 + t) * 32 + quad * 8;
            short8 fa = BAND_FA(64);
            short8 fb0 = *(const short8*)(m2T + (ntb + l16) * 200 + k0q);
            short8 fb1 = *(const short8*)(m2T + (ntb + 16 + l16) * 200 + k0q);
            a0 = __builtin_amdgcn_mfma_f32_16x16x32_bf16(fa, fb0, a0, 0, 0, 0);
            a1 = __builtin_amdgcn_mfma_f32_16x16x32_bf16(fa, fb1, a1, 0, 0, 0);
        }
#pragma unroll
        for (int nt = 0; nt < 2; ++nt) {
            f32x4 a = nt ? a1 : a0;
            int n = ntb + nt * 16 + l16;
            float o[4];
#pragma unroll
            for (int r = 0; r < 4; ++r) {
                int gm = min(max(i0 - 32 + mtb + quad * 4 + r, 0), S_LEN - 1);
                o[r] = 0.9f * a[r] + 0.1f * v[(size_t)gm * E_DIM + c0 + n];
            }
            *(unsigned*)(m3T + n * 136 + mtb + quad * 4)     = pk2(o[0], o[1]);
            *(unsigned*)(m3T + n * 136 + mtb + quad * 4 + 2) = pk2(o[2], o[3]);
        }
    }
    __syncthreads();   // m2T reads done; m3T visible

    // ---- s4: h5 rows (0..63) -> global bf16. roff 96.
    {
        int u = wave;
        int mtb = (u >> 1) * 16;
        int ntb = (u & 1) * 32;
        f32x4 a0 = {0.f,0.f,0.f,0.f}, a1 = a0;
        int ks0 = mtb >> 5;
        const int m = mtb + l16;
#pragma unroll
        for (int t = 0; t < 3; ++t) {
            int k0q = (ks0 + t) * 32 + quad * 8;
            short8 fa = BAND_FA(96);
            short8 fb0 = *(const short8*)(m3T + (ntb + l16) * 136 + k0q);
            short8 fb1 = *(const short8*)(m3T + (ntb + 16 + l16) * 136 + k0q);
            a0 = __builtin_amdgcn_mfma_f32_16x16x32_bf16(fa, fb0, a0, 0, 0, 0);
            a1 = __builtin_amdgcn_mfma_f32_16x16x32_bf16(fa, fb1, a1, 0, 0, 0);
        }
#pragma unroll
        for (int nt = 0; nt < 2; ++nt) {
            f32x4 a = nt ? a1 : a0;
            int n = ntb + nt * 16 + l16;
#pragma unroll
            for (int r = 0; r < 4; ++r) {
                int gm = i0 + mtb + quad * 4 + r;   // always in range
                float vv = v[(size_t)gm * E_DIM + c0 + n];
                h5b[(size_t)gm * E_DIM + c0 + n] = f2bf(0.9f * a[r] + 0.1f * vv);
            }
        }
    }
#undef BAND_FA
}

// ---------------------------------------------------------------------------
// oln5 (proven R3, unchanged): y = h5 @ Wo + bo + x + LayerNorm.
// A-fragments from global h5b into regs; Wo dbuf with lgkm-only barriers.
// ---------------------------------------------------------------------------
__global__ __launch_bounds__(512)
void oln5(const unsigned short* __restrict__ h5b, const float* __restrict__ Wo,
          const float* __restrict__ bo, const float* __restrict__ x,
          const float* __restrict__ g, const float* __restrict__ lb,
          float* __restrict__ out)
{
    __shared__ unsigned short Bs2[2][512 * 40];
    __shared__ float rsum[8][16], rsq[8][16];
    const int tid = threadIdx.x;
    const int lane = tid & 63, wave = tid >> 6;
    const int quad = lane >> 4, l16 = lane & 15;
    const int m0 = blockIdx.x * 16;
    const int n = tid;

    short8 far_[16];
#pragma unroll
    for (int t = 0; t < 16; ++t)
        far_[t] = *(const short8*)(h5b + (size_t)(m0 + l16) * E_DIM + t * 32 + quad * 8);

    {
        float w0[32];
#pragma unroll
        for (int j = 0; j < 32; ++j)
            w0[j] = Wo[(size_t)j * E_DIM + n];
#pragma unroll
        for (int t = 0; t < 4; ++t) {
            uint4 bp;
            bp.x = pk2(w0[t*8+0], w0[t*8+1]); bp.y = pk2(w0[t*8+2], w0[t*8+3]);
            bp.z = pk2(w0[t*8+4], w0[t*8+5]); bp.w = pk2(w0[t*8+6], w0[t*8+7]);
            *(uint4*)(&Bs2[0][0] + n * 40 + t * 8) = bp;
        }
    }
    LGKM_BARRIER();

    f32x4 acc[4];
#pragma unroll
    for (int t = 0; t < 4; ++t) acc[t] = (f32x4){0.f,0.f,0.f,0.f};

#pragma unroll
    for (int it = 0; it < 16; ++it) {
        float wn[32];
        if (it < 15) {
#pragma unroll
            for (int j = 0; j < 32; ++j)
                wn[j] = Wo[(size_t)((it + 1) * 32 + j) * E_DIM + n];  // in flight
        }

#pragma unroll
        for (int nt = 0; nt < 4; ++nt) {
            short8 fb = *(const short8*)(&Bs2[it & 1][0] +
                                         (wave * 64 + nt * 16 + l16) * 40 + quad * 8);
            acc[nt] = __builtin_amdgcn_mfma_f32_16x16x32_bf16(far_[it], fb, acc[nt], 0, 0, 0);
        }

        if (it < 15) {
#pragma unroll
            for (int t = 0; t < 4; ++t) {
                uint4 bp;
                bp.x = pk2(wn[t*8+0], wn[t*8+1]); bp.y = pk2(wn[t*8+2], wn[t*8+3]);
                bp.z = pk2(wn[t*8+4], wn[t*8+5]); bp.w = pk2(wn[t*8+6], wn[t*8+7]);
                *(uint4*)(&Bs2[(it + 1) & 1][0] + n * 40 + t * 8) = bp;
            }
            LGKM_BARRIER();
        }
    }

    float s[4] = {0.f,0.f,0.f,0.f}, s2[4] = {0.f,0.f,0.f,0.f};
#pragma unroll
    for (int nt = 0; nt < 4; ++nt) {
        int nc = wave * 64 + nt * 16 + l16;
        float bv = bo[nc];
#pragma unroll
        for (int r = 0; r < 4; ++r) {
            int m = m0 + quad * 4 + r;
            float vl = acc[nt][r] + bv + x[(size_t)m * E_DIM + nc];
            acc[nt][r] = vl;
            s[r] += vl; s2[r] += vl * vl;
        }
    }
#pragma unroll
    for (int o = 1; o < 16; o <<= 1) {
#pragma unroll
        for (int r = 0; r < 4; ++r) {
            s[r]  += __shfl_xor(s[r], o, 64);
            s2[r] += __shfl_xor(s2[r], o, 64);
        }
    }
    if (l16 == 0) {
#pragma unroll
        for (int r = 0; r < 4; ++r) {
            rsum[wave][quad * 4 + r] = s[r];
            rsq[wave][quad * 4 + r]  = s2[r];
        }
    }
    __syncthreads();
    float mu[4], rs[4];
#pragma unroll
    for (int r = 0; r < 4; ++r) {
        int rl = quad * 4 + r;
        float tot = 0.f, tot2 = 0.f;
#pragma unroll
        for (int w = 0; w < 8; ++w) { tot += rsum[w][rl]; tot2 += rsq[w][rl]; }
        float m_ = tot * (1.f / 512.f);
        float var = tot2 * (1.f / 512.f) - m_ * m_;
        mu[r] = m_; rs[r] = rsqrtf(var + 1e-12f);
    }
#pragma unroll
    for (int nt = 0; nt < 4; ++nt) {
        int nc = wave * 64 + nt * 16 + l16;
        float gv = g[nc], bbv = lb[nc];
#pragma unroll
        for (int r = 0; r < 4; ++r) {
            int m = m0 + quad * 4 + r;
            out[(size_t)m * E_DIM + nc] = (acc[nt][r] - mu[r]) * rs[r] * gv + bbv;
        }
    }
}

// ---------------------------------------------------------------------------
extern "C" void kernel_launch(void* const* d_in, const int* in_sizes, int n_in,
                              void* d_out, int out_size, void* d_ws, size_t ws_size,
                              hipStream_t stream)
{
    const float* x     = (const float*)d_in[0];
    const float* amask = (const float*)d_in[1];
    const float* Wq = (const float*)d_in[4];
    const float* bq = (const float*)d_in[5];
    const float* Wk = (const float*)d_in[6];
    const float* bk = (const float*)d_in[7];
    const float* Wv = (const float*)d_in[8];
    const float* bv = (const float*)d_in[9];
    const float* Wo = (const float*)d_in[10];
    const float* bo = (const float*)d_in[11];
    const float* lng = (const float*)d_in[12];
    const float* lnb = (const float*)d_in[13];
    float* out = (float*)d_out;

    float* ws = (float*)d_ws;
    float* q  = ws;
    float* k  = ws + (size_t)NE;
    float* v  = ws + (size_t)2 * NE;
    unsigned short* Pb  = (unsigned short*)(ws + (size_t)3 * NE);  // PN u16
    unsigned short* hAb = Pb + (size_t)PN;                          // NE u16
    unsigned short* h5b = hAb + (size_t)NE;                         // NE u16

    qkv_gemm<<<dim3(8, 32, 3), 256, 0, stream>>>(x, Wq, bq, Wk, bk, Wv, bv, q, k, v);

    scores_d1<<<dim3(64, 8), 256, 0, stream>>>(q, k, v, amask, Pb, hAb);  // P + step 1

    diffuse4m<<<dim3(32, 8), 512, 0, stream>>>(hAb, v, Pb, h5b);          // steps 2-5

    oln5<<<128, 512, 0, stream>>>(h5b, Wo, bo, x, lng, lnb, out);         // GEMM + LN
}

// Round 7
// 152.622 us; speedup vs baseline: 2.8000x; 1.0163x over previous
//
#include <hip/hip_runtime.h>
#include <math.h>

#define S_LEN 2048
#define E_DIM 512
#define NE (S_LEN * E_DIM)
#define H_NUM 8
#define WH 32
#define NOFF 65
#define PROW (H_NUM * NOFF) /* 520 */
#define PN (S_LEN * PROW)

typedef float f32x4 __attribute__((ext_vector_type(4)));
typedef short short8 __attribute__((ext_vector_type(8)));

__device__ __forceinline__ unsigned short f2bf(float f) {
    union { float f; unsigned u; } cv; cv.f = f;
    unsigned u = cv.u;
    u += 0x7fffu + ((u >> 16) & 1u);   // RNE
    return (unsigned short)(u >> 16);
}
__device__ __forceinline__ unsigned pk2(float x, float y) {
    return (unsigned)f2bf(x) | ((unsigned)f2bf(y) << 16);
}
__device__ __forceinline__ float bf2f(unsigned short u) {
    union { unsigned u; float f; } cv; cv.u = ((unsigned)u) << 16; return cv.f;
}

// Raw barrier: lgkmcnt(0) only, no vmcnt drain (T3/T4 minimum form).
#define LGKM_BARRIER() do {                                   \
    __builtin_amdgcn_sched_barrier(0);                        \
    asm volatile("s_waitcnt lgkmcnt(0)" ::: "memory");        \
    __builtin_amdgcn_s_barrier();                             \
    __builtin_amdgcn_sched_barrier(0);                        \
} while (0)

// ---------------------------------------------------------------------------
// qkv (proven core; R7: v output now written directly as bf16 via Cb path).
// ---------------------------------------------------------------------------
__device__ __forceinline__ void mfma_gemm_f32(
    const float* __restrict__ A, const float* __restrict__ W,
    const float* __restrict__ bias, float* __restrict__ C,
    unsigned short* __restrict__ Cb, float scale, int m0, int n0)
{
    __shared__ unsigned short As[2][64 * 40];
    __shared__ unsigned short Bs[2][64 * 40];
    const int tid = threadIdx.x;
    const int lane = tid & 63, wave = tid >> 6;
    const int quad = lane >> 4, l16 = lane & 15;
    const int wr = (wave >> 1) * 32, wc = (wave & 1) * 32;
    const int ar = tid >> 2, ac = (tid & 3) * 8;
    const int bn = tid & 63, bk0 = (tid >> 6) * 8;

    f32x4 acc00 = {0.f,0.f,0.f,0.f}, acc01 = acc00, acc10 = acc00, acc11 = acc00;

    const float* Arow = A + (size_t)(m0 + ar) * E_DIM;

    float4 a0r[2], a1r[2];
    float  br[2][8];

#define QLOAD(s_, i_) do {                                                    \
        int kk_ = (i_) * 32;                                                  \
        a0r[s_] = *(const float4*)(Arow + kk_ + ac);                          \
        a1r[s_] = *(const float4*)(Arow + kk_ + ac + 4);                      \
        _Pragma("unroll")                                                     \
        for (int j_ = 0; j_ < 8; ++j_)                                        \
            br[s_][j_] = W[(size_t)(kk_ + bk0 + j_) * E_DIM + n0 + bn];       \
    } while (0)

#define QPACK(s_, b_) do {                                                    \
        uint4 ap_;                                                            \
        ap_.x = pk2(a0r[s_].x, a0r[s_].y); ap_.y = pk2(a0r[s_].z, a0r[s_].w); \
        ap_.z = pk2(a1r[s_].x, a1r[s_].y); ap_.w = pk2(a1r[s_].z, a1r[s_].w); \
        *(uint4*)(&As[b_][0] + ar * 40 + ac) = ap_;                           \
        uint4 bp_;                                                            \
        bp_.x = pk2(br[s_][0], br[s_][1]); bp_.y = pk2(br[s_][2], br[s_][3]); \
        bp_.z = pk2(br[s_][4], br[s_][5]); bp_.w = pk2(br[s_][6], br[s_][7]); \
        *(uint4*)(&Bs[b_][0] + bn * 40 + bk0) = bp_;                          \
    } while (0)

    QLOAD(0, 0);
    QPACK(0, 0);
    QLOAD(1, 1);
    LGKM_BARRIER();

#pragma unroll
    for (int it = 0; it < 16; ++it) {
        if (it < 14) QLOAD(it & 1, it + 2);

        const unsigned short* Ab = &As[it & 1][0];
        const unsigned short* Bb = &Bs[it & 1][0];
        short8 fa0 = *(const short8*)(Ab + (wr + l16) * 40 + quad * 8);
        short8 fa1 = *(const short8*)(Ab + (wr + 16 + l16) * 40 + quad * 8);
        short8 fb0 = *(const short8*)(Bb + (wc + l16) * 40 + quad * 8);
        short8 fb1 = *(const short8*)(Bb + (wc + 16 + l16) * 40 + quad * 8);
        acc00 = __builtin_amdgcn_mfma_f32_16x16x32_bf16(fa0, fb0, acc00, 0, 0, 0);
        acc01 = __builtin_amdgcn_mfma_f32_16x16x32_bf16(fa0, fb1, acc01, 0, 0, 0);
        acc10 = __builtin_amdgcn_mfma_f32_16x16x32_bf16(fa1, fb0, acc10, 0, 0, 0);
        acc11 = __builtin_amdgcn_mfma_f32_16x16x32_bf16(fa1, fb1, acc11, 0, 0, 0);

        if (it < 15) {
            QPACK((it + 1) & 1, (it + 1) & 1);
            LGKM_BARRIER();
        }
    }
#undef QLOAD
#undef QPACK

#pragma unroll
    for (int mi = 0; mi < 2; ++mi) {
#pragma unroll
        for (int ni = 0; ni < 2; ++ni) {
            f32x4 a = (mi == 0) ? ((ni == 0) ? acc00 : acc01)
                                : ((ni == 0) ? acc10 : acc11);
            int n = n0 + wc + ni * 16 + l16;
            float bval = bias[n];
#pragma unroll
            for (int r = 0; r < 4; ++r) {
                int m = m0 + wr + mi * 16 + quad * 4 + r;
                if (Cb) Cb[(size_t)m * E_DIM + n] = f2bf((a[r] + bval) * scale);
                else    C [(size_t)m * E_DIM + n] = (a[r] + bval) * scale;
            }
        }
    }
}

__global__ __launch_bounds__(256)
void qkv_gemm(const float* __restrict__ x,
              const float* __restrict__ Wq, const float* __restrict__ bq,
              const float* __restrict__ Wk, const float* __restrict__ bk,
              const float* __restrict__ Wv, const float* __restrict__ bv,
              float* __restrict__ q, float* __restrict__ k,
              unsigned short* __restrict__ vb)
{
    if (blockIdx.z == 0)
        mfma_gemm_f32(x, Wq, bq, q, nullptr, 0.125f, blockIdx.y * 64, blockIdx.x * 64);
    else if (blockIdx.z == 1)
        mfma_gemm_f32(x, Wk, bk, k, nullptr, 1.0f, blockIdx.y * 64, blockIdx.x * 64);
    else
        mfma_gemm_f32(x, Wv, bv, nullptr, vb, 1.0f, blockIdx.y * 64, blockIdx.x * 64);
}

// ---------------------------------------------------------------------------
// scores_d1 (R7): scores f32 in regs + shuffle softmax (proven), then
// diffusion step 1 as BANDED MFMA (replaces the 66-iter VALU PV loop):
//   psb[32][136] shifted band layout (R6-proven alignment algebra),
//   vT[64][104] transposed bf16 v rows [i0-32, i0+64).
// v input is bf16 (vb). 2 barriers (was 3). LDS 48.5 KB -> 3 blocks/CU.
// ---------------------------------------------------------------------------
#define SDN 32
__global__ __launch_bounds__(256)
void scores_d1(const float* __restrict__ q, const float* __restrict__ k,
               const unsigned short* __restrict__ vb, const float* __restrict__ amask,
               unsigned short* __restrict__ Pb, unsigned short* __restrict__ hAb)
{
    const int i0 = blockIdx.x * SDN;
    const int h  = blockIdx.y;
    const int tid = threadIdx.x;
    const int lane = tid & 63, wave = tid >> 6;
    const int quad = lane >> 4, l16 = lane & 15;
    __shared__ float ks[96 * 68];              // k rows [i0-32,i0+64) f32
    __shared__ float am[96];
    __shared__ unsigned short vT[64 * 104];    // [col][vrow 0..95] bf16
    __shared__ unsigned short psb[32 * 136];   // shifted band P rows bf16

    // zero psb (pads stay zero; band overwritten post-S1)
    for (int e = tid; e < 32 * 68; e += 256)
        ((unsigned*)psb)[e] = 0u;

    // stage k rows f32
    for (int e = tid; e < 96 * 16; e += 256) {
        int lr = e >> 4, c4 = e & 15;
        int j = i0 - WH + lr;
        int jc = min(max(j, 0), S_LEN - 1);
        *(float4*)(ks + lr * 68 + c4 * 4) =
            *(const float4*)(k + (size_t)jc * E_DIM + h * 64 + c4 * 4);
    }
    // stage vT transposed bf16 (row pairs packed per col)
    for (int e = tid; e < 48 * 16; e += 256) {
        int rp = (e >> 4) * 2, c4 = (e & 15) * 4;
        int ja = min(max(i0 - WH + rp,     0), S_LEN - 1);
        int jb = min(max(i0 - WH + rp + 1, 0), S_LEN - 1);
        ushort4 va = *(const ushort4*)(vb + (size_t)ja * E_DIM + h * 64 + c4);
        ushort4 vc = *(const ushort4*)(vb + (size_t)jb * E_DIM + h * 64 + c4);
        *(unsigned*)(vT + (c4 + 0) * 104 + rp) = (unsigned)va.x | ((unsigned)vc.x << 16);
        *(unsigned*)(vT + (c4 + 1) * 104 + rp) = (unsigned)va.y | ((unsigned)vc.y << 16);
        *(unsigned*)(vT + (c4 + 2) * 104 + rp) = (unsigned)va.z | ((unsigned)vc.z << 16);
        *(unsigned*)(vT + (c4 + 3) * 104 + rp) = (unsigned)va.w | ((unsigned)vc.w << 16);
    }
    if (tid < 96) {
        int j = i0 - WH + tid;
        am[tid] = (j >= 0 && j < S_LEN) ? amask[j] : -1.0f;
    }

    const int dst = tid >> 3;
    const int og  = tid & 7;
    float4 qreg[16];
    {
        const float4* qrow = (const float4*)(q + (size_t)(i0 + dst) * E_DIM + h * 64);
#pragma unroll
        for (int t = 0; t < 16; ++t) qreg[t] = qrow[t];
    }
    __syncthreads();                        // S1: ks/vT/am/psb-zero staged

    float sreg[9];
#pragma unroll
    for (int t = 0; t < 9; ++t) sreg[t] = -INFINITY;
#pragma unroll
    for (int t = 0; t < 9; ++t) {
        int off = og + 8 * t;
        if (off > 64) break;
        int j = i0 + dst + off - WH;
        if (j >= 0 && j < S_LEN) {
            int lr = dst + off;
            const float4* kr = (const float4*)(ks + lr * 68);
            float acc = 0.f;
#pragma unroll
            for (int u = 0; u < 16; ++u) {
                float4 a = qreg[u], bb = kr[u];
                acc += a.x * bb.x + a.y * bb.y + a.z * bb.z + a.w * bb.w;
            }
            sreg[t] = (am[lr] >= 0.f) ? acc : -1e9f;
        }
    }

    // shuffle softmax over the 8-lane group sharing dst
    float mx = sreg[0];
#pragma unroll
    for (int t = 1; t < 9; ++t) mx = fmaxf(mx, sreg[t]);
#pragma unroll
    for (int o = 1; o < 8; o <<= 1) mx = fmaxf(mx, __shfl_xor(mx, o, 64));
    float dn = 0.f;
#pragma unroll
    for (int t = 0; t < 9; ++t) {
        sreg[t] = expf(sreg[t] - mx);
        dn += sreg[t];
    }
#pragma unroll
    for (int o = 1; o < 8; o <<= 1) dn += __shfl_xor(dn, o, 64);
    float rinv = 1.f / dn;
#pragma unroll
    for (int t = 0; t < 9; ++t) {
        int off = og + 8 * t;
        if (off > 64) break;
        unsigned short pv16 = f2bf(sreg[t] * rinv);
        Pb[(size_t)(i0 + dst) * PROW + h * NOFF + off] = pv16;
        psb[dst * 136 + 32 + (dst & 7) + off] = pv16;
    }
    __syncthreads();                        // S2: psb band filled

    // banded MFMA PV: 8 units (2 m-tiles x 4 n-tiles) over 4 waves
#pragma unroll
    for (int uu = 0; uu < 2; ++uu) {
        int u = wave * 2 + uu;
        int mtb = (u >> 2) * 16;
        int ntb = (u & 3) * 16;
        const int m = mtb + l16;
        f32x4 a0 = {0.f,0.f,0.f,0.f};
#pragma unroll
        for (int t = 0; t < 3; ++t) {
            int k0q = t * 32 + quad * 8;
            short8 fa = *(const short8*)(psb + m * 136 + 32 + (m & 7) + (k0q - m));
            short8 fb = *(const short8*)(vT + (ntb + l16) * 104 + k0q);
            a0 = __builtin_amdgcn_mfma_f32_16x16x32_bf16(fa, fb, a0, 0, 0, 0);
        }
#pragma unroll
        for (int r = 0; r < 4; ++r) {
            int grow = mtb + quad * 4 + r;       // 0..31
            int gcol = ntb + l16;                // 0..63
            float vv = bf2f(vT[gcol * 104 + WH + grow]);
            float o = 0.9f * a0[r] + 0.1f * vv;
            hAb[(size_t)(i0 + grow) * E_DIM + h * 64 + gcol] = f2bf(o);
        }
    }
}

// ---------------------------------------------------------------------------
// diffuse4m (R6 structure; R7: v reads from bf16 vb). Steps 2-5 banded MFMA
// with zero-padded shifted band layout ps2[256][136] (one ds_read_b128/frag).
// LDS 145408 B, 1 block/CU.
// ---------------------------------------------------------------------------
__global__ __launch_bounds__(512)
void diffuse4m(const unsigned short* __restrict__ hAb, const unsigned short* __restrict__ vb,
               const unsigned short* __restrict__ Pb, unsigned short* __restrict__ h5b)
{
    __shared__ unsigned short inT[64 * 328];  // h1: 320 rows [i0-128,i0+192)
    __shared__ unsigned short m1T[64 * 264];  // h2: 256 rows [i0-96,i0+160)
    __shared__ unsigned short ps2[256 * 136]; // padded/shifted band rows
    unsigned short* m2T = inT;                // h3: 192 rows, stride 200
    unsigned short* m3T = m1T;                // h4: 128 rows, stride 136
    const int i0 = blockIdx.x * 64;
    const int h  = blockIdx.y;
    const int c0 = h * 64;
    const int tid  = threadIdx.x;
    const int lane = tid & 63, wave = tid >> 6;
    const int quad = lane >> 4, l16 = lane & 15;

    // zero ps2 (pass 1)
    for (int e = tid; e < 256 * 68; e += 512)
        ((unsigned*)ps2)[e] = 0u;

    // stage h1 (320 rows, bf16 source) -> inT transposed
    for (int e = tid; e < 160 * 16; e += 512) {
        int rp = (e >> 4) * 2, c4 = (e & 15) * 4;
        int ja = min(max(i0 - 128 + rp,     0), S_LEN - 1);
        int jb = min(max(i0 - 128 + rp + 1, 0), S_LEN - 1);
        ushort4 ha = *(const ushort4*)(hAb + (size_t)ja * E_DIM + c0 + c4);
        ushort4 hb = *(const ushort4*)(hAb + (size_t)jb * E_DIM + c0 + c4);
        *(unsigned*)(inT + (c4 + 0) * 328 + rp) = (unsigned)ha.x | ((unsigned)hb.x << 16);
        *(unsigned*)(inT + (c4 + 1) * 328 + rp) = (unsigned)ha.y | ((unsigned)hb.y << 16);
        *(unsigned*)(inT + (c4 + 2) * 328 + rp) = (unsigned)ha.z | ((unsigned)hb.z << 16);
        *(unsigned*)(inT + (c4 + 3) * 328 + rp) = (unsigned)ha.w | ((unsigned)hb.w << 16);
    }
    __syncthreads();   // zeros visible before band fill overwrites

    // band fill (pass 2): wave w handles rows w, w+8, ...
    for (int it = 0; it < 32; ++it) {
        int row = wave + it * 8;
        int jc = min(max(i0 - 96 + row, 0), S_LEN - 1);
        const unsigned short* src = Pb + (size_t)jc * PROW + h * NOFF;
        unsigned short* dst = ps2 + row * 136 + 32 + (row & 7);
        dst[lane] = src[lane];
        if (lane == 0) dst[64] = src[64];
    }
    __syncthreads();

#define BAND_FA(roff_)                                                        \
    *(const short8*)(ps2 + (size_t)(m + (roff_)) * 136 + 32 +                 \
                     ((m + (roff_)) & 7) + (k0q - m))

    // ---- s1: h2 rows (0..255), inT -> m1T. roff 0.
#pragma unroll
    for (int uu = 0; uu < 4; ++uu) {
        int u = wave + uu * 8;
        int mtb = (u >> 1) * 16;
        int ntb = (u & 1) * 32;
        f32x4 a0 = {0.f,0.f,0.f,0.f}, a1 = a0;
        int ks0 = mtb >> 5;
        const int m = mtb + l16;
#pragma unroll
        for (int t = 0; t < 3; ++t) {
            int k0q = (ks0 + t) * 32 + quad * 8;
            short8 fa = BAND_FA(0);
            short8 fb0 = *(const short8*)(inT + (ntb + l16) * 328 + k0q);
            short8 fb1 = *(const short8*)(inT + (ntb + 16 + l16) * 328 + k0q);
            a0 = __builtin_amdgcn_mfma_f32_16x16x32_bf16(fa, fb0, a0, 0, 0, 0);
            a1 = __builtin_amdgcn_mfma_f32_16x16x32_bf16(fa, fb1, a1, 0, 0, 0);
        }
#pragma unroll
        for (int nt = 0; nt < 2; ++nt) {
            f32x4 a = nt ? a1 : a0;
            int n = ntb + nt * 16 + l16;
            float o[4];
#pragma unroll
            for (int r = 0; r < 4; ++r) {
                int gm = min(max(i0 - 96 + mtb + quad * 4 + r, 0), S_LEN - 1);
                o[r] = 0.9f * a[r] + 0.1f * bf2f(vb[(size_t)gm * E_DIM + c0 + n]);
            }
            *(unsigned*)(m1T + n * 264 + mtb + quad * 4)     = pk2(o[0], o[1]);
            *(unsigned*)(m1T + n * 264 + mtb + quad * 4 + 2) = pk2(o[2], o[3]);
        }
    }
    __syncthreads();   // inT reads done -> m2T overlay safe; m1T visible

    // ---- s2: h3 rows (0..191), m1T -> m2T. roff 32.
#pragma unroll
    for (int uu = 0; uu < 3; ++uu) {
        int u = wave + uu * 8;
        int mtb = (u >> 1) * 16;
        int ntb = (u & 1) * 32;
        f32x4 a0 = {0.f,0.f,0.f,0.f}, a1 = a0;
        int ks0 = mtb >> 5;
        const int m = mtb + l16;
#pragma unroll
        for (int t = 0; t < 3; ++t) {
            int k0q = (ks0 + t) * 32 + quad * 8;
            short8 fa = BAND_FA(32);
            short8 fb0 = *(const short8*)(m1T + (ntb + l16) * 264 + k0q);
            short8 fb1 = *(const short8*)(m1T + (ntb + 16 + l16) * 264 + k0q);
            a0 = __builtin_amdgcn_mfma_f32_16x16x32_bf16(fa, fb0, a0, 0, 0, 0);
            a1 = __builtin_amdgcn_mfma_f32_16x16x32_bf16(fa, fb1, a1, 0, 0, 0);
        }
#pragma unroll
        for (int nt = 0; nt < 2; ++nt) {
            f32x4 a = nt ? a1 : a0;
            int n = ntb + nt * 16 + l16;
            float o[4];
#pragma unroll
            for (int r = 0; r < 4; ++r) {
                int gm = min(max(i0 - 64 + mtb + quad * 4 + r, 0), S_LEN - 1);
                o[r] = 0.9f * a[r] + 0.1f * bf2f(vb[(size_t)gm * E_DIM + c0 + n]);
            }
            *(unsigned*)(m2T + n * 200 + mtb + quad * 4)     = pk2(o[0], o[1]);
            *(unsigned*)(m2T + n * 200 + mtb + quad * 4 + 2) = pk2(o[2], o[3]);
        }
    }
    __syncthreads();   // m1T reads done -> m3T overlay safe; m2T visible

    // ---- s3: h4 rows (0..127), m2T -> m3T. roff 64.
#pragma unroll
    for (int uu = 0; uu < 2; ++uu) {
        int u = wave + uu * 8;
        int mtb = (u >> 1) * 16;
        int ntb = (u & 1) * 32;
        f32x4 a0 = {0.f,0.f,0.f,0.f}, a1 = a0;
        int ks0 = mtb >> 5;
        const int m = mtb + l16;
#pragma unroll
        for (int t = 0; t < 3; ++t) {
            int k0q = (ks0 + t) * 32 + quad * 8;
            short8 fa = BAND_FA(64);
            short8 fb0 = *(const short8*)(m2T + (ntb + l16) * 200 + k0q);
            short8 fb1 = *(const short8*)(m2T + (ntb + 16 + l16) * 200 + k0q);
            a0 = __builtin_amdgcn_mfma_f32_16x16x32_bf16(fa, fb0, a0, 0, 0, 0);
            a1 = __builtin_amdgcn_mfma_f32_16x16x32_bf16(fa, fb1, a1, 0, 0, 0);
        }
#pragma unroll
        for (int nt = 0; nt < 2; ++nt) {
            f32x4 a = nt ? a1 : a0;
            int n = ntb + nt * 16 + l16;
            float o[4];
#pragma unroll
            for (int r = 0; r < 4; ++r) {
                int gm = min(max(i0 - 32 + mtb + quad * 4 + r, 0), S_LEN - 1);
                o[r] = 0.9f * a[r] + 0.1f * bf2f(vb[(size_t)gm * E_DIM + c0 + n]);
            }
            *(unsigned*)(m3T + n * 136 + mtb + quad * 4)     = pk2(o[0], o[1]);
            *(unsigned*)(m3T + n * 136 + mtb + quad * 4 + 2) = pk2(o[2], o[3]);
        }
    }
    __syncthreads();   // m2T reads done; m3T visible

    // ---- s4: h5 rows (0..63) -> global bf16. roff 96.
    {
        int u = wave;
        int mtb = (u >> 1) * 16;
        int ntb = (u & 1) * 32;
        f32x4 a0 = {0.f,0.f,0.f,0.f}, a1 = a0;
        int ks0 = mtb >> 5;
        const int m = mtb + l16;
#pragma unroll
        for (int t = 0; t < 3; ++t) {
            int k0q = (ks0 + t) * 32 + quad * 8;
            short8 fa = BAND_FA(96);
            short8 fb0 = *(const short8*)(m3T + (ntb + l16) * 136 + k0q);
            short8 fb1 = *(const short8*)(m3T + (ntb + 16 + l16) * 136 + k0q);
            a0 = __builtin_amdgcn_mfma_f32_16x16x32_bf16(fa, fb0, a0, 0, 0, 0);
            a1 = __builtin_amdgcn_mfma_f32_16x16x32_bf16(fa, fb1, a1, 0, 0, 0);
        }
#pragma unroll
        for (int nt = 0; nt < 2; ++nt) {
            f32x4 a = nt ? a1 : a0;
            int n = ntb + nt * 16 + l16;
#pragma unroll
            for (int r = 0; r < 4; ++r) {
                int gm = i0 + mtb + quad * 4 + r;   // always in range
                float vv = bf2f(vb[(size_t)gm * E_DIM + c0 + n]);
                h5b[(size_t)gm * E_DIM + c0 + n] = f2bf(0.9f * a[r] + 0.1f * vv);
            }
        }
    }
#undef BAND_FA
}

// ---------------------------------------------------------------------------
// oln5 (proven R3, unchanged): y = h5 @ Wo + bo + x + LayerNorm.
// ---------------------------------------------------------------------------
__global__ __launch_bounds__(512)
void oln5(const unsigned short* __restrict__ h5b, const float* __restrict__ Wo,
          const float* __restrict__ bo, const float* __restrict__ x,
          const float* __restrict__ g, const float* __restrict__ lb,
          float* __restrict__ out)
{
    __shared__ unsigned short Bs2[2][512 * 40];
    __shared__ float rsum[8][16], rsq[8][16];
    const int tid = threadIdx.x;
    const int lane = tid & 63, wave = tid >> 6;
    const int quad = lane >> 4, l16 = lane & 15;
    const int m0 = blockIdx.x * 16;
    const int n = tid;

    short8 far_[16];
#pragma unroll
    for (int t = 0; t < 16; ++t)
        far_[t] = *(const short8*)(h5b + (size_t)(m0 + l16) * E_DIM + t * 32 + quad * 8);

    {
        float w0[32];
#pragma unroll
        for (int j = 0; j < 32; ++j)
            w0[j] = Wo[(size_t)j * E_DIM + n];
#pragma unroll
        for (int t = 0; t < 4; ++t) {
            uint4 bp;
            bp.x = pk2(w0[t*8+0], w0[t*8+1]); bp.y = pk2(w0[t*8+2], w0[t*8+3]);
            bp.z = pk2(w0[t*8+4], w0[t*8+5]); bp.w = pk2(w0[t*8+6], w0[t*8+7]);
            *(uint4*)(&Bs2[0][0] + n * 40 + t * 8) = bp;
        }
    }
    LGKM_BARRIER();

    f32x4 acc[4];
#pragma unroll
    for (int t = 0; t < 4; ++t) acc[t] = (f32x4){0.f,0.f,0.f,0.f};

#pragma unroll
    for (int it = 0; it < 16; ++it) {
        float wn[32];
        if (it < 15) {
#pragma unroll
            for (int j = 0; j < 32; ++j)
                wn[j] = Wo[(size_t)((it + 1) * 32 + j) * E_DIM + n];  // in flight
        }

#pragma unroll
        for (int nt = 0; nt < 4; ++nt) {
            short8 fb = *(const short8*)(&Bs2[it & 1][0] +
                                         (wave * 64 + nt * 16 + l16) * 40 + quad * 8);
            acc[nt] = __builtin_amdgcn_mfma_f32_16x16x32_bf16(far_[it], fb, acc[nt], 0, 0, 0);
        }

        if (it < 15) {
#pragma unroll
            for (int t = 0; t < 4; ++t) {
                uint4 bp;
                bp.x = pk2(wn[t*8+0], wn[t*8+1]); bp.y = pk2(wn[t*8+2], wn[t*8+3]);
                bp.z = pk2(wn[t*8+4], wn[t*8+5]); bp.w = pk2(wn[t*8+6], wn[t*8+7]);
                *(uint4*)(&Bs2[(it + 1) & 1][0] + n * 40 + t * 8) = bp;
            }
            LGKM_BARRIER();
        }
    }

    float s[4] = {0.f,0.f,0.f,0.f}, s2[4] = {0.f,0.f,0.f,0.f};
#pragma unroll
    for (int nt = 0; nt < 4; ++nt) {
        int nc = wave * 64 + nt * 16 + l16;
        float bv = bo[nc];
#pragma unroll
        for (int r = 0; r < 4; ++r) {
            int m = m0 + quad * 4 + r;
            float vl = acc[nt][r] + bv + x[(size_t)m * E_DIM + nc];
            acc[nt][r] = vl;
            s[r] += vl; s2[r] += vl * vl;
        }
    }
#pragma unroll
    for (int o = 1; o < 16; o <<= 1) {
#pragma unroll
        for (int r = 0; r < 4; ++r) {
            s[r]  += __shfl_xor(s[r], o, 64);
            s2[r] += __shfl_xor(s2[r], o, 64);
        }
    }
    if (l16 == 0) {
#pragma unroll
        for (int r = 0; r < 4; ++r) {
            rsum[wave][quad * 4 + r] = s[r];
            rsq[wave][quad * 4 + r]  = s2[r];
        }
    }
    __syncthreads();
    float mu[4], rs[4];
#pragma unroll
    for (int r = 0; r < 4; ++r) {
        int rl = quad * 4 + r;
        float tot = 0.f, tot2 = 0.f;
#pragma unroll
        for (int w = 0; w < 8; ++w) { tot += rsum[w][rl]; tot2 += rsq[w][rl]; }
        float m_ = tot * (1.f / 512.f);
        float var = tot2 * (1.f / 512.f) - m_ * m_;
        mu[r] = m_; rs[r] = rsqrtf(var + 1e-12f);
    }
#pragma unroll
    for (int nt = 0; nt < 4; ++nt) {
        int nc = wave * 64 + nt * 16 + l16;
        float gv = g[nc], bbv = lb[nc];
#pragma unroll
        for (int r = 0; r < 4; ++r) {
            int m = m0 + quad * 4 + r;
            out[(size_t)m * E_DIM + nc] = (acc[nt][r] - mu[r]) * rs[r] * gv + bbv;
        }
    }
}

// ---------------------------------------------------------------------------
extern "C" void kernel_launch(void* const* d_in, const int* in_sizes, int n_in,
                              void* d_out, int out_size, void* d_ws, size_t ws_size,
                              hipStream_t stream)
{
    const float* x     = (const float*)d_in[0];
    const float* amask = (const float*)d_in[1];
    const float* Wq = (const float*)d_in[4];
    const float* bq = (const float*)d_in[5];
    const float* Wk = (const float*)d_in[6];
    const float* bk = (const float*)d_in[7];
    const float* Wv = (const float*)d_in[8];
    const float* bv = (const float*)d_in[9];
    const float* Wo = (const float*)d_in[10];
    const float* bo = (const float*)d_in[11];
    const float* lng = (const float*)d_in[12];
    const float* lnb = (const float*)d_in[13];
    float* out = (float*)d_out;

    float* ws = (float*)d_ws;
    float* q  = ws;
    float* k  = ws + (size_t)NE;
    unsigned short* vb  = (unsigned short*)(ws + (size_t)2 * NE);  // NE u16
    unsigned short* Pb  = vb + (size_t)NE;                          // PN u16
    unsigned short* hAb = Pb + (size_t)PN;                          // NE u16
    unsigned short* h5b = hAb + (size_t)NE;                         // NE u16

    qkv_gemm<<<dim3(8, 32, 3), 256, 0, stream>>>(x, Wq, bq, Wk, bk, Wv, bv, q, k, vb);

    scores_d1<<<dim3(64, 8), 256, 0, stream>>>(q, k, vb, amask, Pb, hAb);  // P + step 1

    diffuse4m<<<dim3(32, 8), 512, 0, stream>>>(hAb, vb, Pb, h5b);          // steps 2-5

    oln5<<<128, 512, 0, stream>>>(h5b, Wo, bo, x, lng, lnb, out);          // GEMM + LN
}